// Round 12
// baseline (544.188 us; speedup 1.0000x reference)
//
#include <hip/hip_runtime.h>
#include <math.h>

#define NG 8
#define C96 96
#define NMID 48
#define HW 56
#define PIX 3136      // 56*56
#define GHW 25088     // 8*3136
#define CIN 768       // 96*8
#define NPIXT 9633792 // 4*96*8*3136
#define BN_N 100352   // 4*8*3136
#define PADW 58
#define PADPIX 3364   // 58*58
#define WTK 589824    // 768*768 per-tap stride in Wt
#define PPL 3968      // padded pool plane: 62 rows x 64 cols

typedef __attribute__((ext_vector_type(8))) short bf16x8;
typedef __attribute__((ext_vector_type(4))) float f32x4;

// ---------- group math (verified rounds 0-11) ----------
__device__ __forceinline__ int d_comp(int a, int b){
  int m1=a>>2, r1=a&3, m2=b>>2, r2=b&3;
  int m=(m1+m2)&1;
  int r = (m2==0) ? (r1+r2) : (r2-r1);
  r = (r+4)&3;
  return 4*m+r;
}
__device__ __forceinline__ int d_inv(int a){ return (a>>2) ? a : ((4-(a&3))&3); }
__device__ __forceinline__ int d_perm(int h, int g){ return d_comp(d_inv(h), g); }

__device__ __forceinline__ void d_src(int h, int dy, int dx, int n, int* sy, int* sx){
  int r=h&3, m=h>>2, e=n-1;
  int y,x;
  if(r==0){y=dy; x=dx;}
  else if(r==1){y=dx; x=e-dy;}
  else if(r==2){y=e-dy; x=e-dx;}
  else {y=e-dx; x=dy;}
  if(m) x = e-x;
  *sy=y; *sx=x;
}

__device__ __forceinline__ unsigned short f2bf(float f){
  unsigned int u = __builtin_bit_cast(unsigned int, f);
  unsigned int r = (u + 0x7FFFu + ((u>>16)&1u)) >> 16;
  return (unsigned short)r;
}

__device__ __forceinline__ void gload_lds16(const void* g, void* l){
  __builtin_amdgcn_global_load_lds((const __attribute__((address_space(1))) unsigned int*)g,
                                   (__attribute__((address_space(3))) unsigned int*)l, 16, 0, 0);
}

#define VMCNT6() do { asm volatile("s_waitcnt vmcnt(6)" ::: "memory"); \
                      __builtin_amdgcn_sched_barrier(0); } while(0)
#define VMCNT2() do { asm volatile("s_waitcnt vmcnt(2)" ::: "memory"); \
                      __builtin_amdgcn_sched_barrier(0); } while(0)
#define VMCNT0() do { asm volatile("s_waitcnt vmcnt(0)" ::: "memory"); \
                      __builtin_amdgcn_sched_barrier(0); } while(0)
#define BAR() do { __builtin_amdgcn_s_barrier(); __builtin_amdgcn_sched_barrier(0); } while(0)

// ---------- BN partial stats: grid (96 c, 8 slices) ----------
__global__ void k_bn_stats(const float* __restrict__ in, float* __restrict__ spart){
  __shared__ float sm[8];
  int c = blockIdx.x, s = blockIdx.y;
  int b = s>>1, half = s&1;
  const float4* p = (const float4*)(in + ((size_t)(b*C96 + c))*GHW) + half*(GHW/8);
  float sum=0.f, sum2=0.f;
  for (int i=threadIdx.x; i<GHW/8; i+=256){
    float4 v = p[i];
    sum  += v.x+v.y+v.z+v.w;
    sum2 += v.x*v.x+v.y*v.y+v.z*v.z+v.w*v.w;
  }
  #pragma unroll
  for (int off=32; off>0; off>>=1){ sum += __shfl_down(sum,off); sum2 += __shfl_down(sum2,off); }
  int lane=threadIdx.x&63, wid=threadIdx.x>>6;
  if(lane==0){ sm[wid]=sum; sm[4+wid]=sum2; }
  __syncthreads();
  if(threadIdx.x==0){
    float a=sm[0]+sm[1]+sm[2]+sm[3], b2=sm[4]+sm[5]+sm[6]+sm[7];
    spart[(c*8+s)*2]   = a;
    spart[(c*8+s)*2+1] = b2;
  }
}

// ---------- spatial pool from raw x (bn+relu in registers) ----------
__global__ __launch_bounds__(256) void k_pool(const float* __restrict__ in,
    const float* __restrict__ spart, const float* __restrict__ gamma, const float* __restrict__ beta,
    float* __restrict__ pp){
  __shared__ float scs[C96], shs[C96];
  int tid = threadIdx.x;
  if (tid < C96){
    float s=0.f, s2=0.f;
    #pragma unroll
    for (int k=0;k<8;k++){ s += spart[(tid*8+k)*2]; s2 += spart[(tid*8+k)*2+1]; }
    float mean = s*(1.f/BN_N);
    float var  = s2*(1.f/BN_N) - mean*mean;
    float sc = gamma[tid]*rsqrtf(var + 2e-5f);
    scs[tid] = sc; shs[tid] = beta[tid] - mean*sc;
  }
  __syncthreads();
  int bg = blockIdx.y; int b = bg>>3, g = bg&7;
  int px = blockIdx.x*256 + tid;
  if (px >= PIX) return;
  float pm = 0.f, pmx = 0.f;
  for (int c = 0; c < C96; c++){
    size_t idx = ((size_t)((b*C96 + c)*8 + g))*PIX + px;
    float v = fmaxf(fmaf(in[idx], scs[c], shs[c]), 0.f);
    pm += v; pmx = fmaxf(pmx, v);
  }
  int y = px/HW, x = px - y*HW;
  pp[(size_t)(b*16 + g)*PPL     + (y+3)*64 + (x+3)] = pm;
  pp[(size_t)(b*16 + 8 + g)*PPL + (y+3)*64 + (x+3)] = pmx;
}

// ---------- channel means from raw x ----------
__global__ void k_chan(const float* __restrict__ in, const float* __restrict__ spart,
    const float* __restrict__ gamma, const float* __restrict__ beta, float* __restrict__ sout){
  int bcg = blockIdx.x;
  int c = (bcg >> 3) % C96;
  float s=0.f, s2=0.f;
  #pragma unroll
  for (int k=0;k<8;k++){ s += spart[(c*8+k)*2]; s2 += spart[(c*8+k)*2+1]; }
  float mean = s*(1.f/BN_N);
  float var  = s2*(1.f/BN_N) - mean*mean;
  float sc = gamma[c]*rsqrtf(var + 2e-5f);
  float sh = beta[c] - mean*sc;
  const float4* p = (const float4*)(in + (size_t)bcg*PIX);
  float acc=0.f;
  for (int i=threadIdx.x; i<PIX/4; i+=64){
    float4 v = p[i];
    acc += fmaxf(fmaf(v.x,sc,sh),0.f) + fmaxf(fmaf(v.y,sc,sh),0.f)
         + fmaxf(fmaf(v.z,sc,sh),0.f) + fmaxf(fmaf(v.w,sc,sh),0.f);
  }
  #pragma unroll
  for(int off=32;off>0;off>>=1) acc += __shfl_down(acc,off);
  if(threadIdx.x==0) sout[bcg] = acc * (1.f/3136.f);
}

// ---------- fused channel attention (ca1 + ca2) ----------
__global__ void k_ca(const float* __restrict__ sbuf, const float* __restrict__ W1,
                     const float* __restrict__ W2, float* __restrict__ ach){
  __shared__ float sl[CIN], tl[NMID*8];
  int b = blockIdx.x, tid = threadIdx.x;
  sl[tid] = sbuf[b*CIN + tid];
  __syncthreads();
  int o = tid & 7;
  int pg[8];
  #pragma unroll
  for (int g=0; g<8; g++) pg[g] = d_perm(o, g);
  if (tid < NMID*8){
    int m = tid >> 3;
    float acc = 0.f;
    for (int c=0; c<C96; c++){
      #pragma unroll
      for (int g=0; g<8; g++) acc += W1[(m*C96+c)*8+pg[g]] * sl[c*8+g];
    }
    tl[tid] = fmaxf(acc, 0.f);
  }
  __syncthreads();
  {
    int c = tid >> 3;
    float acc = 0.f;
    for (int m=0; m<NMID; m++){
      #pragma unroll
      for (int g=0; g<8; g++) acc += W2[(c*NMID+m)*8+pg[g]] * tl[(m<<3)+g];
    }
    ach[b*CIN + tid] = 1.f/(1.f+__expf(-acc));
  }
}

// ---------- spatial attention 7x7 group conv + sigmoid ----------
__global__ __launch_bounds__(256) void k_sp_conv(const float* __restrict__ pp,
    const float* __restrict__ Wsp, float* __restrict__ aspt){
  __shared__ float wl[2*8*49];
  int bh = blockIdx.y; int b=bh>>3, h=bh&7;
  for(int idx=threadIdx.x; idx<784; idx+=256){
    int i = idx/392; int rem = idx-i*392;
    int g = rem/49; int kk = rem-g*49;
    int dy=kk/7, dx=kk-dy*7;
    int pg = d_perm(h,g);
    int sy,sx; d_src(h,dy,dx,7,&sy,&sx);
    wl[idx] = Wsp[(i*8+pg)*49 + sy*7+sx] * (i==0 ? (1.f/96.f) : 1.f);
  }
  __syncthreads();
  int pix = blockIdx.x*256 + threadIdx.x;
  if(pix>=PIX) return;
  int y=pix/HW, x=pix-y*HW;
  const float* base = pp + (size_t)(b*16)*PPL + y*64 + x;
  float acc=0.f;
  for(int ig=0; ig<16; ig++){
    const float* pb = base + (size_t)ig*PPL;
    const float* wb = wl + ig*49;
    #pragma unroll
    for(int dy=0; dy<7; dy++){
      #pragma unroll
      for(int dx=0; dx<7; dx++)
        acc = fmaf(pb[dy*64+dx], wb[dy*7+dx], acc);
    }
  }
  aspt[((size_t)b*PIX + pix)*8 + h] = 1.f/(1.f+__expf(-acc));
}

// ---------- zero: pool buffer + Xp BORDERS only ----------
__global__ void k_zerob(uint4* __restrict__ xp, uint4* __restrict__ pp){
  uint4 z = (uint4){0u,0u,0u,0u};
  int i = blockIdx.x*256 + threadIdx.x;
  if (blockIdx.x < 248){ pp[i] = z; return; }          // 248*256 = 63488 = 4*16*PPL/4
  int r = i - 63488;
  if (r >= 87552) return;                              // 4b * 228 border px * 96 uint4
  int b = r / 21888;
  int q = r - b*21888;
  int p = q / 96, j = q - p*96;
  int y, x;
  if (p < 58){ y=0; x=p; }
  else if (p < 116){ y=57; x=p-58; }
  else if (p < 172){ y=p-115; x=0; }
  else { y=p-171; x=57; }
  xp[(size_t)(b*PADPIX + y*PADW + x)*96 + j] = z;
}

// ---------- fused bn+relu + modulate + transpose + bf16 pack ----------
__global__ __launch_bounds__(256) void k_mod_t(const float* __restrict__ in,
    const float* __restrict__ spart, const float* __restrict__ gamma, const float* __restrict__ beta,
    const float* __restrict__ ach, const float* __restrict__ aspt,
    unsigned int* __restrict__ XpU){
  __shared__ float tile[64][65];
  __shared__ float scs8[8], shs8[8];
  int b = blockIdx.z;
  int cg0 = blockIdx.y*64;
  int pix0 = blockIdx.x*64;
  int tid = threadIdx.x;
  if (tid < 8){
    int c = (cg0>>3) + tid;
    float s=0.f, s2=0.f;
    #pragma unroll
    for (int k=0;k<8;k++){ s += spart[(c*8+k)*2]; s2 += spart[(c*8+k)*2+1]; }
    float mean = s*(1.f/BN_N);
    float var  = s2*(1.f/BN_N) - mean*mean;
    float sc = gamma[c]*rsqrtf(var + 2e-5f);
    scs8[tid] = sc; shs8[tid] = beta[c] - mean*sc;
  }
  __syncthreads();
  int lane = tid & 63, w = tid >> 6;
  for (int r = w; r < 64; r += 4){
    int cg = cg0 + r;
    float a1 = ach[b*CIN + cg];
    float raw = in[(size_t)(b*CIN + cg)*PIX + pix0 + lane];
    float v = fmaxf(fmaf(raw, scs8[r>>3], shs8[r>>3]), 0.f);
    tile[r][lane] = v * a1;
  }
  __syncthreads();
  int half = lane >> 5;
  int cgA = (lane & 31)*2;
  #pragma unroll
  for (int it = 0; it < 8; it++){
    int p = it*8 + w*2 + half;
    int pix = pix0 + p;
    int y = pix/HW, x = pix - y*HW;
    float2 a2 = *(const float2*)(aspt + ((size_t)b*PIX + pix)*8 + (cgA&7));
    float vA = tile[cgA][p]   * a2.x;
    float vB = tile[cgA+1][p] * a2.y;
    unsigned int u = (unsigned int)f2bf(vA) | ((unsigned int)f2bf(vB) << 16);
    XpU[(((size_t)b*PADPIX + (y+1)*PADW + (x+1))*CIN + cg0 + cgA) >> 1] = u;
  }
}

// ---------- weight transform (both layers) ----------
__global__ void k_ktb2(const float* __restrict__ W1src, const float* __restrict__ W2src,
                       unsigned short* __restrict__ Wt1, unsigned short* __restrict__ Wt2){
  const float* W = blockIdx.y ? W2src : W1src;
  unsigned short* Wt = blockIdx.y ? Wt2 : Wt1;
  int idx = blockIdx.x*256 + threadIdx.x;
  int ci = idx % CIN;
  int t2 = idx / CIN;
  int co = t2 % CIN;
  int kk = t2 / CIN;
  int h = co/C96, o = co - h*C96;
  int i = ci >> 3, g = ci & 7;
  int dy = kk/3, dx = kk - dy*3;
  int sy, sx; d_src(h, dy, dx, 3, &sy, &sx);
  float v = W[((o*C96 + i)*8 + d_perm(h,g))*9 + sy*3 + sx];
  Wt[idx] = f2bf(v);
}

// ---------- main conv: BM=128, K-chunk=32, bank-swizzled LDS + X double-buffer ----------
// Grid 672 -> ~3 blocks/CU. LDS 48KB: X dbuf 2x16KB [0,32K) + W dbuf 2x8KB [32K,48K).
// Granule swizzle g' = kg ^ ((px>>1)&3) on global SOURCE (dest forced linear) and on reads:
// within any 16-lane phase group all 32 banks covered 2-way (free, m136). Verified for A and
// B reads at every dx incl. row-wrap. X[c+1] issued at kk=6 (3 taps cover); per-tap waits
// vmcnt(2)/(6); ONE barrier per chunk; vmcnt(0) only in prologue/final tap (T4).
__global__ __launch_bounds__(256, 3) void k_convmf(const unsigned short* __restrict__ Xp,
    const unsigned short* __restrict__ Wt, const float* __restrict__ resid,
    float* __restrict__ out){
  __shared__ unsigned short lds[24576];   // 48KB
  char* ldsb = (char*)lds;
  int tid = threadIdx.x, lane = tid & 63, w = tid >> 6;
  int col = lane & 15, kg = lane >> 4;

  int bid = blockIdx.x;
  int wgid = (bid & 7)*84 + (bid >> 3);       // bijective XCD chunking (672 = 8*84)
  int m = wgid/112; int rem = wgid - m*112;
  int b = rem/28;  int rp = rem - b*28;
  int y0 = rp*2, co0 = m*128;

  // X staging: 4 rounds x 256 thr x 16B = 16KB/buffer; linear dest, SWIZZLED source granule
  int xgo[4], xds[4];
  #pragma unroll
  for (int t = 0; t < 4; t++){
    int slot = t*256 + tid;                   // (row, px, g)
    int row = slot >> 8;
    int px  = (slot >> 2) & 63;
    int g   = slot & 3;
    int sg  = g ^ ((px >> 1) & 3);
    xgo[t] = (b*PADPIX + (y0+row)*PADW + px)*CIN + sg*8;
    xds[t] = slot*16;                         // bytes; + xb*16384 at issue
  }
  // W staging: wave w stages its own rows [w*32,w*32+32): 2 rounds; swizzled source granule
  int wgo[2], wds[2];
  #pragma unroll
  for (int j = 0; j < 2; j++){
    int r  = w*32 + j*16 + (lane>>2);
    int sg = (lane&3) ^ ((lane>>3)&3);        // ((r>>1)&3) == ((lane>>3)&3) here
    wgo[j] = (co0 + r)*CIN + sg*8;
    wds[j] = 32768 + r*64 + (lane&3)*16;      // linear in lane; + (q^1)*8192 at issue
  }
  // A-read byte offsets within a W buffer (parity added per tap)
  int awo[2];
  #pragma unroll
  for (int mf = 0; mf < 2; mf++){
    int r = w*32 + mf*16 + col;
    awo[mf] = 32768 + r*64 + ((kg ^ ((col>>1)&3)) << 4);
  }
  // B-read byte offsets (dx,nf); dy folds to +dyk*4096; xbuf via +xb*16384
  int bb[3][7];
  #pragma unroll
  for (int nf=0; nf<7; nf++){
    int q2 = nf*16 + col;
    int qyl = (q2 >= 56) ? 1 : 0;
    int qx = q2 - 56*qyl;
    #pragma unroll
    for (int dx=0; dx<3; dx++){
      int px = qx + dx;
      bb[dx][nf] = qyl*4096 + px*64 + ((kg ^ ((px>>1)&3)) << 4);
    }
  }

  f32x4 acc[2][7];
  #pragma unroll
  for (int mf=0; mf<2; mf++)
    #pragma unroll
    for (int nf=0; nf<7; nf++)
      acc[mf][nf] = (f32x4){0.f,0.f,0.f,0.f};

  // ---- prologue: W[0] -> buf0, X[0] -> xbuf0; full drain once ----
  #pragma unroll
  for (int j = 0; j < 2; j++) gload_lds16(Wt + wgo[j], ldsb + wds[j]);
  #pragma unroll
  for (int t = 0; t < 4; t++) gload_lds16(Xp + xgo[t], ldsb + xds[t]);
  VMCNT0();
  BAR();

  int q = 0;
  for (int chunk = 0; chunk < 23; chunk++){
    const int xb = (chunk & 1) * 16384;
    #pragma unroll
    for (int kk = 0; kk < 9; kk++){
      // issue W[s+1] into W buf q^1 (wave-private rows)
      {
        int kk2 = (kk == 8) ? 0 : kk+1;
        int c2  = (kk == 8) ? chunk+1 : chunk;
        size_t gofs = (size_t)kk2*WTK + (c2 << 5);
        int dofs = (q^1)*8192;
        gload_lds16(Wt + gofs + wgo[0], ldsb + dofs + wds[0]);
        gload_lds16(Wt + gofs + wgo[1], ldsb + dofs + wds[1]);
      }
      if (kk == 6){                            // issue X[chunk+1] into other X buffer
        #pragma unroll
        for (int t = 0; t < 4; t++)
          gload_lds16(Xp + xgo[t] + (chunk+1)*32, ldsb + (xb^16384) + xds[t]);
      }
      // counted wait for W[s] (and, at kk=8, X[c+1])
      if (kk == 6 || kk == 7) VMCNT6();        // keep W[s+1] + X in flight
      else                    VMCNT2();        // kk<=5: trivial; kk==8: retires X+W[s]
      // A-frags
      const int wq = q*8192;
      bf16x8 A0 = *(const bf16x8*)(ldsb + awo[0] + wq);
      bf16x8 A1 = *(const bf16x8*)(ldsb + awo[1] + wq);
      // B-frags + MFMA
      const int dyk = kk/3, dxk = kk - dyk*3;
      const int dofs2 = xb + dyk*4096;
      __builtin_amdgcn_s_setprio(1);
      #pragma unroll
      for (int nf = 0; nf < 7; nf++){
        bf16x8 B = *(const bf16x8*)(ldsb + bb[dxk][nf] + dofs2);
        acc[0][nf] = __builtin_amdgcn_mfma_f32_16x16x32_bf16(A0, B, acc[0][nf], 0,0,0);
        acc[1][nf] = __builtin_amdgcn_mfma_f32_16x16x32_bf16(A1, B, acc[1][nf], 0,0,0);
      }
      __builtin_amdgcn_s_setprio(0);
      q ^= 1;
    }
    BAR();                                     // X[chunk+1] visible (own writes retired @kk8)
  }
  // ---- tail chunk 23 (no X issue, no trailing barrier) ----
  {
    const int xb = (23 & 1) * 16384;
    #pragma unroll
    for (int kk = 0; kk < 9; kk++){
      if (kk < 8){
        size_t gofs = (size_t)(kk+1)*WTK + (23 << 5);
        int dofs = (q^1)*8192;
        gload_lds16(Wt + gofs + wgo[0], ldsb + dofs + wds[0]);
        gload_lds16(Wt + gofs + wgo[1], ldsb + dofs + wds[1]);
        VMCNT2();
      } else {
        VMCNT0();
      }
      const int wq = q*8192;
      bf16x8 A0 = *(const bf16x8*)(ldsb + awo[0] + wq);
      bf16x8 A1 = *(const bf16x8*)(ldsb + awo[1] + wq);
      const int dyk = kk/3, dxk = kk - dyk*3;
      const int dofs2 = xb + dyk*4096;
      __builtin_amdgcn_s_setprio(1);
      #pragma unroll
      for (int nf = 0; nf < 7; nf++){
        bf16x8 B = *(const bf16x8*)(ldsb + bb[dxk][nf] + dofs2);
        acc[0][nf] = __builtin_amdgcn_mfma_f32_16x16x32_bf16(A0, B, acc[0][nf], 0,0,0);
        acc[1][nf] = __builtin_amdgcn_mfma_f32_16x16x32_bf16(A1, B, acc[1][nf], 0,0,0);
      }
      __builtin_amdgcn_s_setprio(0);
      q ^= 1;
    }
  }

  // ---- epilogue: NCGHW fp32 (+residual) ----
  #pragma unroll
  for (int mf = 0; mf < 2; mf++){
    int co_b = co0 + w*32 + mf*16;            // 16-aligned; never straddles h (96%16==0)
    int h = co_b/C96;
    int ob = co_b - h*C96 + kg*4;
    #pragma unroll
    for (int nf = 0; nf < 7; nf++){
      int qq = nf*16 + col;
      #pragma unroll
      for (int r = 0; r < 4; r++){
        size_t oi = ((size_t)((b*C96 + ob + r)*8 + h))*PIX + y0*56 + qq;
        float v = acc[mf][nf][r];
        if (resid) v += resid[oi];
        out[oi] = v;
      }
    }
  }
}

// ---------- host side ----------
static void run_layer(const float* bn_in,
                      const float* a1W, const float* a2W, const float* spW,
                      const float* bng, const float* bnb,
                      const float* resid, float* convout,
                      float* spart, float* sbuf, float* ach, float* ppP, float* aspt,
                      unsigned short* Wt, unsigned short* Xp, hipStream_t stream)
{
  k_bn_stats<<<dim3(C96,8),256,0,stream>>>(bn_in, spart);
  k_pool<<<dim3(13,32),256,0,stream>>>(bn_in, spart, bng, bnb, ppP);
  k_chan<<<4*C96*NG,64,0,stream>>>(bn_in, spart, bng, bnb, sbuf);
  k_ca<<<4,CIN,0,stream>>>(sbuf, a1W, a2W, ach);
  k_sp_conv<<<dim3(13,32),256,0,stream>>>(ppP, spW, aspt);
  k_mod_t<<<dim3(PIX/64, CIN/64, 4),256,0,stream>>>(bn_in, spart, bng, bnb, ach, aspt, (unsigned int*)Xp);
  k_convmf<<<672,256,0,stream>>>(Xp, Wt, resid, convout);
}

extern "C" void kernel_launch(void* const* d_in, const int* in_sizes, int n_in,
                              void* d_out, int out_size, void* d_ws, size_t ws_size,
                              hipStream_t stream) {
  const float* x    = (const float*)d_in[0];
  const float* bn1g = (const float*)d_in[1];
  const float* bn1b = (const float*)d_in[2];
  const float* bn2g = (const float*)d_in[3];
  const float* bn2b = (const float*)d_in[4];
  const float* c1W  = (const float*)d_in[5];
  const float* c1a1 = (const float*)d_in[6];
  const float* c1a2 = (const float*)d_in[7];
  const float* c1sp = (const float*)d_in[8];
  const float* c2W  = (const float*)d_in[9];
  const float* c2a1 = (const float*)d_in[10];
  const float* c2a2 = (const float*)d_in[11];
  const float* c2sp = (const float*)d_in[12];
  float* out = (float*)d_out;
  float* ws  = (float*)d_ws;

  float* bufA = ws;                                          // 9,633,792 f32
  unsigned short* Wt1 = (unsigned short*)(bufA + NPIXT);     // 5,308,416 bf16
  unsigned short* Wt2 = Wt1 + 9*CIN*CIN;                     // 5,308,416 bf16
  unsigned short* Xp  = Wt2 + 9*CIN*CIN;                     // 10,334,208 bf16
  float* spart = (float*)(Xp + (size_t)4*PADPIX*CIN);        // 1536
  float* sbuf  = spart + 1536;                               // 3072
  float* ach   = sbuf + 4*C96*NG;                            // 3072
  float* ppP   = ach + 4*C96*NG;                             // 253,952 (padded pool)
  float* aspt  = ppP + 4*16*PPL;                             // 100,352
  // total ~= 83 MB

  k_ktb2<<<dim3((9*CIN*CIN)/256, 2),256,0,stream>>>(c1W, c2W, Wt1, Wt2);
  k_zerob<<<590,256,0,stream>>>((uint4*)Xp, (uint4*)ppP);

  // layer 1: bufA = conv_gg(mod(relu(bn1(x))))
  run_layer(x, c1a1, c1a2, c1sp, bn1g, bn1b, nullptr, bufA,
            spart, sbuf, ach, ppP, aspt, Wt1, Xp, stream);
  // layer 2: out = x + conv_gg(mod(relu(bn2(bufA))))
  run_layer(bufA, c2a1, c2a2, c2sp, bn2g, bn2b, x, out,
            spart, sbuf, ach, ppP, aspt, Wt2, Xp, stream);
}

// Round 13
// 485.986 us; speedup vs baseline: 1.1198x; 1.1198x over previous
//
#include <hip/hip_runtime.h>
#include <math.h>

#define NG 8
#define C96 96
#define NMID 48
#define HW 56
#define PIX 3136      // 56*56
#define GHW 25088     // 8*3136
#define CIN 768       // 96*8
#define NPIXT 9633792 // 4*96*8*3136
#define BN_N 100352   // 4*8*3136
#define PADW 58
#define PADPIX 3364   // 58*58
#define WTK 589824    // 768*768 per-tap stride in Wt
#define PPL 3968      // padded pool plane: 62 rows x 64 cols

typedef __attribute__((ext_vector_type(8))) short bf16x8;
typedef __attribute__((ext_vector_type(4))) float f32x4;

// ---------- group math (verified rounds 0-12) ----------
__device__ __forceinline__ int d_comp(int a, int b){
  int m1=a>>2, r1=a&3, m2=b>>2, r2=b&3;
  int m=(m1+m2)&1;
  int r = (m2==0) ? (r1+r2) : (r2-r1);
  r = (r+4)&3;
  return 4*m+r;
}
__device__ __forceinline__ int d_inv(int a){ return (a>>2) ? a : ((4-(a&3))&3); }
__device__ __forceinline__ int d_perm(int h, int g){ return d_comp(d_inv(h), g); }

__device__ __forceinline__ void d_src(int h, int dy, int dx, int n, int* sy, int* sx){
  int r=h&3, m=h>>2, e=n-1;
  int y,x;
  if(r==0){y=dy; x=dx;}
  else if(r==1){y=dx; x=e-dy;}
  else if(r==2){y=e-dy; x=e-dx;}
  else {y=e-dx; x=dy;}
  if(m) x = e-x;
  *sy=y; *sx=x;
}

__device__ __forceinline__ unsigned short f2bf(float f){
  unsigned int u = __builtin_bit_cast(unsigned int, f);
  unsigned int r = (u + 0x7FFFu + ((u>>16)&1u)) >> 16;
  return (unsigned short)r;
}

__device__ __forceinline__ void gload_lds16(const void* g, void* l){
  __builtin_amdgcn_global_load_lds((const __attribute__((address_space(1))) unsigned int*)g,
                                   (__attribute__((address_space(3))) unsigned int*)l, 16, 0, 0);
}

#define VMCNT12() do { asm volatile("s_waitcnt vmcnt(12)" ::: "memory"); \
                       __builtin_amdgcn_sched_barrier(0); } while(0)
#define VMCNT4() do { asm volatile("s_waitcnt vmcnt(4)" ::: "memory"); \
                      __builtin_amdgcn_sched_barrier(0); } while(0)
#define VMCNT0() do { asm volatile("s_waitcnt vmcnt(0)" ::: "memory"); \
                      __builtin_amdgcn_sched_barrier(0); } while(0)
#define BAR() do { __builtin_amdgcn_s_barrier(); __builtin_amdgcn_sched_barrier(0); } while(0)

// ---------- BN partial stats: grid (96 c, 8 slices) ----------
__global__ void k_bn_stats(const float* __restrict__ in, float* __restrict__ spart){
  __shared__ float sm[8];
  int c = blockIdx.x, s = blockIdx.y;
  int b = s>>1, half = s&1;
  const float4* p = (const float4*)(in + ((size_t)(b*C96 + c))*GHW) + half*(GHW/8);
  float sum=0.f, sum2=0.f;
  for (int i=threadIdx.x; i<GHW/8; i+=256){
    float4 v = p[i];
    sum  += v.x+v.y+v.z+v.w;
    sum2 += v.x*v.x+v.y*v.y+v.z*v.z+v.w*v.w;
  }
  #pragma unroll
  for (int off=32; off>0; off>>=1){ sum += __shfl_down(sum,off); sum2 += __shfl_down(sum2,off); }
  int lane=threadIdx.x&63, wid=threadIdx.x>>6;
  if(lane==0){ sm[wid]=sum; sm[4+wid]=sum2; }
  __syncthreads();
  if(threadIdx.x==0){
    float a=sm[0]+sm[1]+sm[2]+sm[3], b2=sm[4]+sm[5]+sm[6]+sm[7];
    spart[(c*8+s)*2]   = a;
    spart[(c*8+s)*2+1] = b2;
  }
}

// ---------- spatial pool from raw x (bn+relu in registers) ----------
__global__ __launch_bounds__(256) void k_pool(const float* __restrict__ in,
    const float* __restrict__ spart, const float* __restrict__ gamma, const float* __restrict__ beta,
    float* __restrict__ pp){
  __shared__ float scs[C96], shs[C96];
  int tid = threadIdx.x;
  if (tid < C96){
    float s=0.f, s2=0.f;
    #pragma unroll
    for (int k=0;k<8;k++){ s += spart[(tid*8+k)*2]; s2 += spart[(tid*8+k)*2+1]; }
    float mean = s*(1.f/BN_N);
    float var  = s2*(1.f/BN_N) - mean*mean;
    float sc = gamma[tid]*rsqrtf(var + 2e-5f);
    scs[tid] = sc; shs[tid] = beta[tid] - mean*sc;
  }
  __syncthreads();
  int bg = blockIdx.y; int b = bg>>3, g = bg&7;
  int px = blockIdx.x*256 + tid;
  if (px >= PIX) return;
  float pm0=0.f, pm1=0.f, mx0=0.f, mx1=0.f;
  for (int c = 0; c < C96; c += 2){
    size_t i0 = ((size_t)((b*C96 + c)*8 + g))*PIX + px;
    size_t i1 = i0 + (size_t)8*PIX;
    float v0 = fmaxf(fmaf(in[i0], scs[c],   shs[c]),   0.f);
    float v1 = fmaxf(fmaf(in[i1], scs[c+1], shs[c+1]), 0.f);
    pm0 += v0; mx0 = fmaxf(mx0, v0);
    pm1 += v1; mx1 = fmaxf(mx1, v1);
  }
  int y = px/HW, x = px - y*HW;
  pp[(size_t)(b*16 + g)*PPL     + (y+3)*64 + (x+3)] = pm0+pm1;
  pp[(size_t)(b*16 + 8 + g)*PPL + (y+3)*64 + (x+3)] = fmaxf(mx0,mx1);
}

// ---------- channel means from raw x ----------
__global__ void k_chan(const float* __restrict__ in, const float* __restrict__ spart,
    const float* __restrict__ gamma, const float* __restrict__ beta, float* __restrict__ sout){
  int bcg = blockIdx.x;
  int c = (bcg >> 3) % C96;
  float s=0.f, s2=0.f;
  #pragma unroll
  for (int k=0;k<8;k++){ s += spart[(c*8+k)*2]; s2 += spart[(c*8+k)*2+1]; }
  float mean = s*(1.f/BN_N);
  float var  = s2*(1.f/BN_N) - mean*mean;
  float sc = gamma[c]*rsqrtf(var + 2e-5f);
  float sh = beta[c] - mean*sc;
  const float4* p = (const float4*)(in + (size_t)bcg*PIX);
  float acc=0.f;
  for (int i=threadIdx.x; i<PIX/4; i+=64){
    float4 v = p[i];
    acc += fmaxf(fmaf(v.x,sc,sh),0.f) + fmaxf(fmaf(v.y,sc,sh),0.f)
         + fmaxf(fmaf(v.z,sc,sh),0.f) + fmaxf(fmaf(v.w,sc,sh),0.f);
  }
  #pragma unroll
  for(int off=32;off>0;off>>=1) acc += __shfl_down(acc,off);
  if(threadIdx.x==0) sout[bcg] = acc * (1.f/3136.f);
}

// ---------- fused channel attention (ca1 + ca2), chains broken 2-way ----------
__global__ void k_ca(const float* __restrict__ sbuf, const float* __restrict__ W1,
                     const float* __restrict__ W2, float* __restrict__ ach){
  __shared__ float sl[CIN], tl[NMID*8];
  int b = blockIdx.x, tid = threadIdx.x;
  sl[tid] = sbuf[b*CIN + tid];
  __syncthreads();
  int o = tid & 7;
  int pg[8];
  #pragma unroll
  for (int g=0; g<8; g++) pg[g] = d_perm(o, g);
  if (tid < NMID*8){
    int m = tid >> 3;
    float a0 = 0.f, a1 = 0.f;
    for (int c=0; c<C96; c+=2){
      #pragma unroll
      for (int g=0; g<8; g++) a0 += W1[(m*C96+c)*8+pg[g]] * sl[c*8+g];
      #pragma unroll
      for (int g=0; g<8; g++) a1 += W1[(m*C96+c+1)*8+pg[g]] * sl[(c+1)*8+g];
    }
    tl[tid] = fmaxf(a0+a1, 0.f);
  }
  __syncthreads();
  {
    int c = tid >> 3;
    float a0 = 0.f, a1 = 0.f;
    for (int m=0; m<NMID; m+=2){
      #pragma unroll
      for (int g=0; g<8; g++) a0 += W2[(c*NMID+m)*8+pg[g]] * tl[(m<<3)+g];
      #pragma unroll
      for (int g=0; g<8; g++) a1 += W2[(c*NMID+m+1)*8+pg[g]] * tl[((m+1)<<3)+g];
    }
    ach[b*CIN + tid] = 1.f/(1.f+__expf(-(a0+a1)));
  }
}

// ---------- spatial attention 7x7 group conv + sigmoid (4 parallel chains) ----------
__global__ __launch_bounds__(256) void k_sp_conv(const float* __restrict__ pp,
    const float* __restrict__ Wsp, float* __restrict__ aspt){
  __shared__ float wl[2*8*49];
  int bh = blockIdx.y; int b=bh>>3, h=bh&7;
  for(int idx=threadIdx.x; idx<784; idx+=256){
    int i = idx/392; int rem = idx-i*392;
    int g = rem/49; int kk = rem-g*49;
    int dy=kk/7, dx=kk-dy*7;
    int pg = d_perm(h,g);
    int sy,sx; d_src(h,dy,dx,7,&sy,&sx);
    wl[idx] = Wsp[(i*8+pg)*49 + sy*7+sx] * (i==0 ? (1.f/96.f) : 1.f);
  }
  __syncthreads();
  int pix = blockIdx.x*256 + threadIdx.x;
  if(pix>=PIX) return;
  int y=pix/HW, x=pix-y*HW;
  const float* base = pp + (size_t)(b*16)*PPL + y*64 + x;
  float ac[4] = {0.f,0.f,0.f,0.f};
  #pragma unroll
  for(int ig=0; ig<16; ig++){
    const float* pb = base + (size_t)ig*PPL;
    const float* wb = wl + ig*49;
    #pragma unroll
    for(int dy=0; dy<7; dy++){
      #pragma unroll
      for(int dx=0; dx<7; dx++)
        ac[ig&3] = fmaf(pb[dy*64+dx], wb[dy*7+dx], ac[ig&3]);
    }
  }
  float acc = (ac[0]+ac[1]) + (ac[2]+ac[3]);
  aspt[((size_t)b*PIX + pix)*8 + h] = 1.f/(1.f+__expf(-acc));
}

// ---------- zero: pool buffer + Xp BORDERS only ----------
__global__ void k_zerob(uint4* __restrict__ xp, uint4* __restrict__ pp){
  uint4 z = (uint4){0u,0u,0u,0u};
  int i = blockIdx.x*256 + threadIdx.x;
  if (blockIdx.x < 248){ pp[i] = z; return; }          // 248*256 = 63488 = 4*16*PPL/4
  int r = i - 63488;
  if (r >= 87552) return;                              // 4b * 228 border px * 96 uint4
  int b = r / 21888;
  int q = r - b*21888;
  int p = q / 96, j = q - p*96;
  int y, x;
  if (p < 58){ y=0; x=p; }
  else if (p < 116){ y=57; x=p-58; }
  else if (p < 172){ y=p-115; x=0; }
  else { y=p-171; x=57; }
  xp[(size_t)(b*PADPIX + y*PADW + x)*96 + j] = z;
}

// ---------- fused bn+relu + modulate + transpose + bf16 pack ----------
__global__ __launch_bounds__(256) void k_mod_t(const float* __restrict__ in,
    const float* __restrict__ spart, const float* __restrict__ gamma, const float* __restrict__ beta,
    const float* __restrict__ ach, const float* __restrict__ aspt,
    unsigned int* __restrict__ XpU){
  __shared__ float tile[64][65];
  __shared__ float scs8[8], shs8[8];
  int b = blockIdx.z;
  int cg0 = blockIdx.y*64;
  int pix0 = blockIdx.x*64;
  int tid = threadIdx.x;
  if (tid < 8){
    int c = (cg0>>3) + tid;
    float s=0.f, s2=0.f;
    #pragma unroll
    for (int k=0;k<8;k++){ s += spart[(c*8+k)*2]; s2 += spart[(c*8+k)*2+1]; }
    float mean = s*(1.f/BN_N);
    float var  = s2*(1.f/BN_N) - mean*mean;
    float sc = gamma[c]*rsqrtf(var + 2e-5f);
    scs8[tid] = sc; shs8[tid] = beta[c] - mean*sc;
  }
  __syncthreads();
  int lane = tid & 63, w = tid >> 6;
  for (int r = w; r < 64; r += 4){
    int cg = cg0 + r;
    float a1 = ach[b*CIN + cg];
    float raw = in[(size_t)(b*CIN + cg)*PIX + pix0 + lane];
    float v = fmaxf(fmaf(raw, scs8[r>>3], shs8[r>>3]), 0.f);
    tile[r][lane] = v * a1;
  }
  __syncthreads();
  int half = lane >> 5;
  int cgA = (lane & 31)*2;
  #pragma unroll
  for (int it = 0; it < 8; it++){
    int p = it*8 + w*2 + half;
    int pix = pix0 + p;
    int y = pix/HW, x = pix - y*HW;
    float2 a2 = *(const float2*)(aspt + ((size_t)b*PIX + pix)*8 + (cgA&7));
    float vA = tile[cgA][p]   * a2.x;
    float vB = tile[cgA+1][p] * a2.y;
    unsigned int u = (unsigned int)f2bf(vA) | ((unsigned int)f2bf(vB) << 16);
    XpU[(((size_t)b*PADPIX + (y+1)*PADW + (x+1))*CIN + cg0 + cgA) >> 1] = u;
  }
}

// ---------- weight transform (both layers) ----------
__global__ void k_ktb2(const float* __restrict__ W1src, const float* __restrict__ W2src,
                       unsigned short* __restrict__ Wt1, unsigned short* __restrict__ Wt2){
  const float* W = blockIdx.y ? W2src : W1src;
  unsigned short* Wt = blockIdx.y ? Wt2 : Wt1;
  int idx = blockIdx.x*256 + threadIdx.x;
  int ci = idx % CIN;
  int t2 = idx / CIN;
  int co = t2 % CIN;
  int kk = t2 / CIN;
  int h = co/C96, o = co - h*C96;
  int i = ci >> 3, g = ci & 7;
  int dy = kk/3, dx = kk - dy*3;
  int sy, sx; d_src(h, dy, dx, 3, &sy, &sx);
  float v = W[((o*C96 + i)*8 + d_perm(h,g))*9 + sy*3 + sx];
  Wt[idx] = f2bf(v);
}

// ---------- main conv: LDS-BW fix — wave tile 64co x 112px (4m x 7n), 2 waves/block ----------
// 28 MFMA per 11 b128 reads (0.39 r/MFMA vs 0.64 before) -> LDS-BW ceiling ~53% MfmaUtil.
// Block 128 thr, BM=128, BN=112, K=32. Grid 672 = 8x84 XCD-chunked, 3 blocks/CU (6 waves).
// LDS 48KB: X dbuf 2x16KB [0,32K) + W dbuf 2x8KB [32K,48K). Bank swizzle g'=kg^((px>>1)&3)
// on global source + reads (round-12-verified, conflicts=0). Wave w stages+reads only W rows
// [w*64,w*64+64) -> per-wave counted vmcnt, no W barrier; ONE barrier per chunk.
// vmcnt audit: kk0-5: (4); kk6,7: (12) [X+W(s+1) in flight]; kk8: (4) [retires X+W(s)].
__global__ __launch_bounds__(128, 2) void k_convmf(const unsigned short* __restrict__ Xp,
    const unsigned short* __restrict__ Wt, const float* __restrict__ resid,
    float* __restrict__ out){
  __shared__ unsigned short lds[24576];   // 48KB
  char* ldsb = (char*)lds;
  int tid = threadIdx.x, lane = tid & 63, w = tid >> 6;   // w in {0,1}
  int col = lane & 15, kg = lane >> 4;

  int bid = blockIdx.x;
  int wgid = (bid & 7)*84 + (bid >> 3);       // bijective XCD chunking (672 = 8*84)
  int m = wgid/112; int rem = wgid - m*112;
  int b = rem/28;  int rp = rem - b*28;
  int y0 = rp*2, co0 = m*128;

  // X staging: 8 rounds x 128 thr x 16B = 16KB/buffer; linear dest, swizzled source granule
  int xgo[8], xds[8];
  #pragma unroll
  for (int t = 0; t < 8; t++){
    int slot = t*128 + tid;                   // 0..1023 -> (row, px, g)
    int row = slot >> 8;
    int px  = (slot >> 2) & 63;
    int g   = slot & 3;
    int sg  = g ^ ((px >> 1) & 3);
    xgo[t] = (b*PADPIX + (y0+row)*PADW + px)*CIN + sg*8;
    xds[t] = slot*16;                         // bytes; + xb at issue
  }
  // W staging: wave w stages its own rows [w*64,w*64+64): 4 rounds x 64 lanes x 16B
  int wgo[4], wds[4];
  #pragma unroll
  for (int j = 0; j < 4; j++){
    int r  = w*64 + j*16 + (lane>>2);
    int sg = (lane&3) ^ ((lane>>3)&3);        // ((r>>1)&3) == ((lane>>3)&3) here
    wgo[j] = (co0 + r)*CIN + sg*8;
    wds[j] = 32768 + r*64 + (lane&3)*16;      // + (q^1)*8192 at issue
  }
  // A-read byte offsets within a W buffer (parity added per tap)
  int awo[4];
  #pragma unroll
  for (int mf = 0; mf < 4; mf++){
    int r = w*64 + mf*16 + col;
    awo[mf] = 32768 + r*64 + ((kg ^ ((col>>1)&3)) << 4);
  }
  // B-read byte offsets (dx,nf); dy folds to +dyk*4096; xbuf via +xb
  int bb[3][7];
  #pragma unroll
  for (int nf=0; nf<7; nf++){
    int q2 = nf*16 + col;
    int qyl = (q2 >= 56) ? 1 : 0;
    int qx = q2 - 56*qyl;
    #pragma unroll
    for (int dx=0; dx<3; dx++){
      int px = qx + dx;
      bb[dx][nf] = qyl*4096 + px*64 + ((kg ^ ((px>>1)&3)) << 4);
    }
  }

  f32x4 acc[4][7];
  #pragma unroll
  for (int mf=0; mf<4; mf++)
    #pragma unroll
    for (int nf=0; nf<7; nf++)
      acc[mf][nf] = (f32x4){0.f,0.f,0.f,0.f};

  // ---- prologue: W[0] -> par0, X[0] -> xbuf0; full drain once ----
  #pragma unroll
  for (int j = 0; j < 4; j++) gload_lds16(Wt + wgo[j], ldsb + wds[j]);
  #pragma unroll
  for (int t = 0; t < 8; t++) gload_lds16(Xp + xgo[t], ldsb + xds[t]);
  VMCNT0();
  BAR();

  int q = 0;
  for (int chunk = 0; chunk < 23; chunk++){
    const int xb = (chunk & 1) * 16384;
    #pragma unroll
    for (int kk = 0; kk < 9; kk++){
      // issue W[s+1] into W buf q^1 (wave-private rows)
      {
        int kk2 = (kk == 8) ? 0 : kk+1;
        int c2  = (kk == 8) ? chunk+1 : chunk;
        size_t gofs = (size_t)kk2*WTK + (c2 << 5);
        int dofs = (q^1)*8192;
        #pragma unroll
        for (int j = 0; j < 4; j++)
          gload_lds16(Wt + gofs + wgo[j], ldsb + dofs + wds[j]);
      }
      if (kk == 6){                            // issue X[chunk+1] into other X buffer
        #pragma unroll
        for (int t = 0; t < 8; t++)
          gload_lds16(Xp + xgo[t] + (chunk+1)*32, ldsb + (xb^16384) + xds[t]);
      }
      // counted wait: retire W[s] (and, at kk=8, X[c+1]); keep newer loads in flight
      if (kk == 6 || kk == 7) VMCNT12();
      else                    VMCNT4();        // kk<=5 trivial; kk==8 retires X+W[s]
      // A-frags (own W slice)
      const int wq = q*8192;
      bf16x8 A0 = *(const bf16x8*)(ldsb + awo[0] + wq);
      bf16x8 A1 = *(const bf16x8*)(ldsb + awo[1] + wq);
      bf16x8 A2 = *(const bf16x8*)(ldsb + awo[2] + wq);
      bf16x8 A3 = *(const bf16x8*)(ldsb + awo[3] + wq);
      // B-frags + MFMA (B reused 4x from registers)
      const int dyk = kk/3, dxk = kk - dyk*3;
      const int dofs2 = xb + dyk*4096;
      __builtin_amdgcn_s_setprio(1);
      #pragma unroll
      for (int nf = 0; nf < 7; nf++){
        bf16x8 B = *(const bf16x8*)(ldsb + bb[dxk][nf] + dofs2);
        acc[0][nf] = __builtin_amdgcn_mfma_f32_16x16x32_bf16(A0, B, acc[0][nf], 0,0,0);
        acc[1][nf] = __builtin_amdgcn_mfma_f32_16x16x32_bf16(A1, B, acc[1][nf], 0,0,0);
        acc[2][nf] = __builtin_amdgcn_mfma_f32_16x16x32_bf16(A2, B, acc[2][nf], 0,0,0);
        acc[3][nf] = __builtin_amdgcn_mfma_f32_16x16x32_bf16(A3, B, acc[3][nf], 0,0,0);
      }
      __builtin_amdgcn_s_setprio(0);
      q ^= 1;
    }
    BAR();                                     // X[chunk+1] visible (own writes retired @kk8)
  }
  // ---- tail chunk 23 (no X issue, no trailing barrier) ----
  {
    const int xb = 16384;                      // 23&1 = 1
    #pragma unroll
    for (int kk = 0; kk < 9; kk++){
      if (kk < 8){
        size_t gofs = (size_t)(kk+1)*WTK + (23 << 5);
        int dofs = (q^1)*8192;
        #pragma unroll
        for (int j = 0; j < 4; j++)
          gload_lds16(Wt + gofs + wgo[j], ldsb + dofs + wds[j]);
        VMCNT4();
      } else {
        VMCNT0();
      }
      const int wq = q*8192;
      bf16x8 A0 = *(const bf16x8*)(ldsb + awo[0] + wq);
      bf16x8 A1 = *(const bf16x8*)(ldsb + awo[1] + wq);
      bf16x8 A2 = *(const bf16x8*)(ldsb + awo[2] + wq);
      bf16x8 A3 = *(const bf16x8*)(ldsb + awo[3] + wq);
      const int dyk = kk/3, dxk = kk - dyk*3;
      const int dofs2 = xb + dyk*4096;
      __builtin_amdgcn_s_setprio(1);
      #pragma unroll
      for (int nf = 0; nf < 7; nf++){
        bf16x8 B = *(const bf16x8*)(ldsb + bb[dxk][nf] + dofs2);
        acc[0][nf] = __builtin_amdgcn_mfma_f32_16x16x32_bf16(A0, B, acc[0][nf], 0,0,0);
        acc[1][nf] = __builtin_amdgcn_mfma_f32_16x16x32_bf16(A1, B, acc[1][nf], 0,0,0);
        acc[2][nf] = __builtin_amdgcn_mfma_f32_16x16x32_bf16(A2, B, acc[2][nf], 0,0,0);
        acc[3][nf] = __builtin_amdgcn_mfma_f32_16x16x32_bf16(A3, B, acc[3][nf], 0,0,0);
      }
      __builtin_amdgcn_s_setprio(0);
      q ^= 1;
    }
  }

  // ---- epilogue: NCGHW fp32 (+residual) ----
  #pragma unroll
  for (int mf = 0; mf < 4; mf++){
    int co_b = co0 + w*64 + mf*16;             // 16-aligned; never straddles h (96%16==0)
    int h = co_b/C96;
    int ob = co_b - h*C96 + kg*4;
    #pragma unroll
    for (int nf = 0; nf < 7; nf++){
      int qq = nf*16 + col;
      #pragma unroll
      for (int r = 0; r < 4; r++){
        size_t oi = ((size_t)((b*C96 + ob + r)*8 + h))*PIX + y0*56 + qq;
        float v = acc[mf][nf][r];
        if (resid) v += resid[oi];
        out[oi] = v;
      }
    }
  }
}

// ---------- host side ----------
static void run_layer(const float* bn_in,
                      const float* a1W, const float* a2W, const float* spW,
                      const float* bng, const float* bnb,
                      const float* resid, float* convout,
                      float* spart, float* sbuf, float* ach, float* ppP, float* aspt,
                      unsigned short* Wt, unsigned short* Xp, hipStream_t stream)
{
  k_bn_stats<<<dim3(C96,8),256,0,stream>>>(bn_in, spart);
  k_pool<<<dim3(13,32),256,0,stream>>>(bn_in, spart, bng, bnb, ppP);
  k_chan<<<4*C96*NG,64,0,stream>>>(bn_in, spart, bng, bnb, sbuf);
  k_ca<<<4,CIN,0,stream>>>(sbuf, a1W, a2W, ach);
  k_sp_conv<<<dim3(13,32),256,0,stream>>>(ppP, spW, aspt);
  k_mod_t<<<dim3(PIX/64, CIN/64, 4),256,0,stream>>>(bn_in, spart, bng, bnb, ach, aspt, (unsigned int*)Xp);
  k_convmf<<<672,128,0,stream>>>(Xp, Wt, resid, convout);
}

extern "C" void kernel_launch(void* const* d_in, const int* in_sizes, int n_in,
                              void* d_out, int out_size, void* d_ws, size_t ws_size,
                              hipStream_t stream) {
  const float* x    = (const float*)d_in[0];
  const float* bn1g = (const float*)d_in[1];
  const float* bn1b = (const float*)d_in[2];
  const float* bn2g = (const float*)d_in[3];
  const float* bn2b = (const float*)d_in[4];
  const float* c1W  = (const float*)d_in[5];
  const float* c1a1 = (const float*)d_in[6];
  const float* c1a2 = (const float*)d_in[7];
  const float* c1sp = (const float*)d_in[8];
  const float* c2W  = (const float*)d_in[9];
  const float* c2a1 = (const float*)d_in[10];
  const float* c2a2 = (const float*)d_in[11];
  const float* c2sp = (const float*)d_in[12];
  float* out = (float*)d_out;
  float* ws  = (float*)d_ws;

  float* bufA = ws;                                          // 9,633,792 f32
  unsigned short* Wt1 = (unsigned short*)(bufA + NPIXT);     // 5,308,416 bf16
  unsigned short* Wt2 = Wt1 + 9*CIN*CIN;                     // 5,308,416 bf16
  unsigned short* Xp  = Wt2 + 9*CIN*CIN;                     // 10,334,208 bf16
  float* spart = (float*)(Xp + (size_t)4*PADPIX*CIN);        // 1536
  float* sbuf  = spart + 1536;                               // 3072
  float* ach   = sbuf + 4*C96*NG;                            // 3072
  float* ppP   = ach + 4*C96*NG;                             // 253,952 (padded pool)
  float* aspt  = ppP + 4*16*PPL;                             // 100,352
  // total ~= 83 MB

  k_ktb2<<<dim3((9*CIN*CIN)/256, 2),256,0,stream>>>(c1W, c2W, Wt1, Wt2);
  k_zerob<<<590,256,0,stream>>>((uint4*)Xp, (uint4*)ppP);

  // layer 1: bufA = conv_gg(mod(relu(bn1(x))))
  run_layer(x, c1a1, c1a2, c1sp, bn1g, bn1b, nullptr, bufA,
            spart, sbuf, ach, ppP, aspt, Wt1, Xp, stream);
  // layer 2: out = x + conv_gg(mod(relu(bn2(bufA))))
  run_layer(bufA, c2a1, c2a2, c2sp, bn2g, bn2b, x, out,
            spart, sbuf, ach, ppP, aspt, Wt2, Xp, stream);
}

// Round 14
// 471.379 us; speedup vs baseline: 1.1545x; 1.0310x over previous
//
#include <hip/hip_runtime.h>
#include <math.h>

#define NG 8
#define C96 96
#define NMID 48
#define HW 56
#define PIX 3136      // 56*56
#define GHW 25088     // 8*3136
#define CIN 768       // 96*8
#define NPIXT 9633792 // 4*96*8*3136
#define BN_N 100352   // 4*8*3136
#define PADW 58
#define PADPIX 3364   // 58*58
#define WTK 589824    // 768*768 per-tap stride in Wt
#define PPL 3968      // padded pool plane: 62 rows x 64 cols

typedef __attribute__((ext_vector_type(8))) short bf16x8;
typedef __attribute__((ext_vector_type(4))) float f32x4;

// ---------- group math (verified rounds 0-13) ----------
__device__ __forceinline__ int d_comp(int a, int b){
  int m1=a>>2, r1=a&3, m2=b>>2, r2=b&3;
  int m=(m1+m2)&1;
  int r = (m2==0) ? (r1+r2) : (r2-r1);
  r = (r+4)&3;
  return 4*m+r;
}
__device__ __forceinline__ int d_inv(int a){ return (a>>2) ? a : ((4-(a&3))&3); }
__device__ __forceinline__ int d_perm(int h, int g){ return d_comp(d_inv(h), g); }

__device__ __forceinline__ void d_src(int h, int dy, int dx, int n, int* sy, int* sx){
  int r=h&3, m=h>>2, e=n-1;
  int y,x;
  if(r==0){y=dy; x=dx;}
  else if(r==1){y=dx; x=e-dy;}
  else if(r==2){y=e-dy; x=e-dx;}
  else {y=e-dx; x=dy;}
  if(m) x = e-x;
  *sy=y; *sx=x;
}

__device__ __forceinline__ unsigned short f2bf(float f){
  unsigned int u = __builtin_bit_cast(unsigned int, f);
  unsigned int r = (u + 0x7FFFu + ((u>>16)&1u)) >> 16;
  return (unsigned short)r;
}

__device__ __forceinline__ void gload_lds16(const void* g, void* l){
  __builtin_amdgcn_global_load_lds((const __attribute__((address_space(1))) unsigned int*)g,
                                   (__attribute__((address_space(3))) unsigned int*)l, 16, 0, 0);
}

#define VMCNT6() do { asm volatile("s_waitcnt vmcnt(6)" ::: "memory"); \
                      __builtin_amdgcn_sched_barrier(0); } while(0)
#define VMCNT2() do { asm volatile("s_waitcnt vmcnt(2)" ::: "memory"); \
                      __builtin_amdgcn_sched_barrier(0); } while(0)
#define VMCNT0() do { asm volatile("s_waitcnt vmcnt(0)" ::: "memory"); \
                      __builtin_amdgcn_sched_barrier(0); } while(0)
#define BAR() do { __builtin_amdgcn_s_barrier(); __builtin_amdgcn_sched_barrier(0); } while(0)

// ---------- BN partial stats: grid (96 c, 8 slices) ----------
__global__ void k_bn_stats(const float* __restrict__ in, float* __restrict__ spart){
  __shared__ float sm[8];
  int c = blockIdx.x, s = blockIdx.y;
  int b = s>>1, half = s&1;
  const float4* p = (const float4*)(in + ((size_t)(b*C96 + c))*GHW) + half*(GHW/8);
  float sum=0.f, sum2=0.f;
  for (int i=threadIdx.x; i<GHW/8; i+=256){
    float4 v = p[i];
    sum  += v.x+v.y+v.z+v.w;
    sum2 += v.x*v.x+v.y*v.y+v.z*v.z+v.w*v.w;
  }
  #pragma unroll
  for (int off=32; off>0; off>>=1){ sum += __shfl_down(sum,off); sum2 += __shfl_down(sum2,off); }
  int lane=threadIdx.x&63, wid=threadIdx.x>>6;
  if(lane==0){ sm[wid]=sum; sm[4+wid]=sum2; }
  __syncthreads();
  if(threadIdx.x==0){
    float a=sm[0]+sm[1]+sm[2]+sm[3], b2=sm[4]+sm[5]+sm[6]+sm[7];
    spart[(c*8+s)*2]   = a;
    spart[(c*8+s)*2+1] = b2;
  }
}

// ---------- spatial pool from raw x (bn+relu in registers, 2-way chains) ----------
__global__ __launch_bounds__(256) void k_pool(const float* __restrict__ in,
    const float* __restrict__ spart, const float* __restrict__ gamma, const float* __restrict__ beta,
    float* __restrict__ pp){
  __shared__ float scs[C96], shs[C96];
  int tid = threadIdx.x;
  if (tid < C96){
    float s=0.f, s2=0.f;
    #pragma unroll
    for (int k=0;k<8;k++){ s += spart[(tid*8+k)*2]; s2 += spart[(tid*8+k)*2+1]; }
    float mean = s*(1.f/BN_N);
    float var  = s2*(1.f/BN_N) - mean*mean;
    float sc = gamma[tid]*rsqrtf(var + 2e-5f);
    scs[tid] = sc; shs[tid] = beta[tid] - mean*sc;
  }
  __syncthreads();
  int bg = blockIdx.y; int b = bg>>3, g = bg&7;
  int px = blockIdx.x*256 + tid;
  if (px >= PIX) return;
  float pm0=0.f, pm1=0.f, mx0=0.f, mx1=0.f;
  for (int c = 0; c < C96; c += 2){
    size_t i0 = ((size_t)((b*C96 + c)*8 + g))*PIX + px;
    size_t i1 = i0 + (size_t)8*PIX;
    float v0 = fmaxf(fmaf(in[i0], scs[c],   shs[c]),   0.f);
    float v1 = fmaxf(fmaf(in[i1], scs[c+1], shs[c+1]), 0.f);
    pm0 += v0; mx0 = fmaxf(mx0, v0);
    pm1 += v1; mx1 = fmaxf(mx1, v1);
  }
  int y = px/HW, x = px - y*HW;
  pp[(size_t)(b*16 + g)*PPL     + (y+3)*64 + (x+3)] = pm0+pm1;
  pp[(size_t)(b*16 + 8 + g)*PPL + (y+3)*64 + (x+3)] = fmaxf(mx0,mx1);
}

// ---------- channel means from raw x ----------
__global__ void k_chan(const float* __restrict__ in, const float* __restrict__ spart,
    const float* __restrict__ gamma, const float* __restrict__ beta, float* __restrict__ sout){
  int bcg = blockIdx.x;
  int c = (bcg >> 3) % C96;
  float s=0.f, s2=0.f;
  #pragma unroll
  for (int k=0;k<8;k++){ s += spart[(c*8+k)*2]; s2 += spart[(c*8+k)*2+1]; }
  float mean = s*(1.f/BN_N);
  float var  = s2*(1.f/BN_N) - mean*mean;
  float sc = gamma[c]*rsqrtf(var + 2e-5f);
  float sh = beta[c] - mean*sc;
  const float4* p = (const float4*)(in + (size_t)bcg*PIX);
  float acc=0.f;
  for (int i=threadIdx.x; i<PIX/4; i+=64){
    float4 v = p[i];
    acc += fmaxf(fmaf(v.x,sc,sh),0.f) + fmaxf(fmaf(v.y,sc,sh),0.f)
         + fmaxf(fmaf(v.z,sc,sh),0.f) + fmaxf(fmaf(v.w,sc,sh),0.f);
  }
  #pragma unroll
  for(int off=32;off>0;off>>=1) acc += __shfl_down(acc,off);
  if(threadIdx.x==0) sout[bcg] = acc * (1.f/3136.f);
}

// ---------- fused channel attention (ca1 + ca2), chains broken 2-way ----------
__global__ void k_ca(const float* __restrict__ sbuf, const float* __restrict__ W1,
                     const float* __restrict__ W2, float* __restrict__ ach){
  __shared__ float sl[CIN], tl[NMID*8];
  int b = blockIdx.x, tid = threadIdx.x;
  sl[tid] = sbuf[b*CIN + tid];
  __syncthreads();
  int o = tid & 7;
  int pg[8];
  #pragma unroll
  for (int g=0; g<8; g++) pg[g] = d_perm(o, g);
  if (tid < NMID*8){
    int m = tid >> 3;
    float a0 = 0.f, a1 = 0.f;
    for (int c=0; c<C96; c+=2){
      #pragma unroll
      for (int g=0; g<8; g++) a0 += W1[(m*C96+c)*8+pg[g]] * sl[c*8+g];
      #pragma unroll
      for (int g=0; g<8; g++) a1 += W1[(m*C96+c+1)*8+pg[g]] * sl[(c+1)*8+g];
    }
    tl[tid] = fmaxf(a0+a1, 0.f);
  }
  __syncthreads();
  {
    int c = tid >> 3;
    float a0 = 0.f, a1 = 0.f;
    for (int m=0; m<NMID; m+=2){
      #pragma unroll
      for (int g=0; g<8; g++) a0 += W2[(c*NMID+m)*8+pg[g]] * tl[(m<<3)+g];
      #pragma unroll
      for (int g=0; g<8; g++) a1 += W2[(c*NMID+m+1)*8+pg[g]] * tl[((m+1)<<3)+g];
    }
    ach[b*CIN + tid] = 1.f/(1.f+__expf(-(a0+a1)));
  }
}

// ---------- spatial attention 7x7 group conv + sigmoid (4 parallel chains) ----------
__global__ __launch_bounds__(256) void k_sp_conv(const float* __restrict__ pp,
    const float* __restrict__ Wsp, float* __restrict__ aspt){
  __shared__ float wl[2*8*49];
  int bh = blockIdx.y; int b=bh>>3, h=bh&7;
  for(int idx=threadIdx.x; idx<784; idx+=256){
    int i = idx/392; int rem = idx-i*392;
    int g = rem/49; int kk = rem-g*49;
    int dy=kk/7, dx=kk-dy*7;
    int pg = d_perm(h,g);
    int sy,sx; d_src(h,dy,dx,7,&sy,&sx);
    wl[idx] = Wsp[(i*8+pg)*49 + sy*7+sx] * (i==0 ? (1.f/96.f) : 1.f);
  }
  __syncthreads();
  int pix = blockIdx.x*256 + threadIdx.x;
  if(pix>=PIX) return;
  int y=pix/HW, x=pix-y*HW;
  const float* base = pp + (size_t)(b*16)*PPL + y*64 + x;
  float ac[4] = {0.f,0.f,0.f,0.f};
  #pragma unroll
  for(int ig=0; ig<16; ig++){
    const float* pb = base + (size_t)ig*PPL;
    const float* wb = wl + ig*49;
    #pragma unroll
    for(int dy=0; dy<7; dy++){
      #pragma unroll
      for(int dx=0; dx<7; dx++)
        ac[ig&3] = fmaf(pb[dy*64+dx], wb[dy*7+dx], ac[ig&3]);
    }
  }
  float acc = (ac[0]+ac[1]) + (ac[2]+ac[3]);
  aspt[((size_t)b*PIX + pix)*8 + h] = 1.f/(1.f+__expf(-acc));
}

// ---------- zero: pool buffer + Xp BORDERS only ----------
__global__ void k_zerob(uint4* __restrict__ xp, uint4* __restrict__ pp){
  uint4 z = (uint4){0u,0u,0u,0u};
  int i = blockIdx.x*256 + threadIdx.x;
  if (blockIdx.x < 248){ pp[i] = z; return; }          // 248*256 = 63488 = 4*16*PPL/4
  int r = i - 63488;
  if (r >= 87552) return;                              // 4b * 228 border px * 96 uint4
  int b = r / 21888;
  int q = r - b*21888;
  int p = q / 96, j = q - p*96;
  int y, x;
  if (p < 58){ y=0; x=p; }
  else if (p < 116){ y=57; x=p-58; }
  else if (p < 172){ y=p-115; x=0; }
  else { y=p-171; x=57; }
  xp[(size_t)(b*PADPIX + y*PADW + x)*96 + j] = z;
}

// ---------- fused bn+relu + modulate + transpose + bf16 pack ----------
__global__ __launch_bounds__(256) void k_mod_t(const float* __restrict__ in,
    const float* __restrict__ spart, const float* __restrict__ gamma, const float* __restrict__ beta,
    const float* __restrict__ ach, const float* __restrict__ aspt,
    unsigned int* __restrict__ XpU){
  __shared__ float tile[64][65];
  __shared__ float scs8[8], shs8[8];
  int b = blockIdx.z;
  int cg0 = blockIdx.y*64;
  int pix0 = blockIdx.x*64;
  int tid = threadIdx.x;
  if (tid < 8){
    int c = (cg0>>3) + tid;
    float s=0.f, s2=0.f;
    #pragma unroll
    for (int k=0;k<8;k++){ s += spart[(c*8+k)*2]; s2 += spart[(c*8+k)*2+1]; }
    float mean = s*(1.f/BN_N);
    float var  = s2*(1.f/BN_N) - mean*mean;
    float sc = gamma[c]*rsqrtf(var + 2e-5f);
    scs8[tid] = sc; shs8[tid] = beta[c] - mean*sc;
  }
  __syncthreads();
  int lane = tid & 63, w = tid >> 6;
  for (int r = w; r < 64; r += 4){
    int cg = cg0 + r;
    float a1 = ach[b*CIN + cg];
    float raw = in[(size_t)(b*CIN + cg)*PIX + pix0 + lane];
    float v = fmaxf(fmaf(raw, scs8[r>>3], shs8[r>>3]), 0.f);
    tile[r][lane] = v * a1;
  }
  __syncthreads();
  int half = lane >> 5;
  int cgA = (lane & 31)*2;
  #pragma unroll
  for (int it = 0; it < 8; it++){
    int p = it*8 + w*2 + half;
    int pix = pix0 + p;
    int y = pix/HW, x = pix - y*HW;
    float2 a2 = *(const float2*)(aspt + ((size_t)b*PIX + pix)*8 + (cgA&7));
    float vA = tile[cgA][p]   * a2.x;
    float vB = tile[cgA+1][p] * a2.y;
    unsigned int u = (unsigned int)f2bf(vA) | ((unsigned int)f2bf(vB) << 16);
    XpU[(((size_t)b*PADPIX + (y+1)*PADW + (x+1))*CIN + cg0 + cgA) >> 1] = u;
  }
}

// ---------- weight transform (both layers) ----------
__global__ void k_ktb2(const float* __restrict__ W1src, const float* __restrict__ W2src,
                       unsigned short* __restrict__ Wt1, unsigned short* __restrict__ Wt2){
  const float* W = blockIdx.y ? W2src : W1src;
  unsigned short* Wt = blockIdx.y ? Wt2 : Wt1;
  int idx = blockIdx.x*256 + threadIdx.x;
  int ci = idx % CIN;
  int t2 = idx / CIN;
  int co = t2 % CIN;
  int kk = t2 / CIN;
  int h = co/C96, o = co - h*C96;
  int i = ci >> 3, g = ci & 7;
  int dy = kk/3, dx = kk - dy*3;
  int sy, sx; d_src(h, dy, dx, 3, &sy, &sx);
  float v = W[((o*C96 + i)*8 + d_perm(h,g))*9 + sy*3 + sx];
  Wt[idx] = f2bf(v);
}

// ---------- main conv: round-12 config (best measured: 147us, MfmaUtil 39%) ----------
// BM=128, K-chunk=32, 256 thr (4 waves, wave 32co x 112px). Grid 672 = 8x84 XCD-chunked,
// 3 blocks/CU. LDS 48KB: X dbuf 2x16KB [0,32K) + W dbuf 2x8KB [32K,48K).
// Bank swizzle g' = kg ^ ((px>>1)&3) on global SOURCE + reads (verified: conflicts=0).
// Wave w stages+reads only W rows [w*32,w*32+32) -> per-wave counted vmcnt, no W barrier.
// X[c+1] issued at kk=6; waits: kk<=5:(2), kk6,7:(6), kk8:(2); ONE barrier per chunk.
__global__ __launch_bounds__(256, 3) void k_convmf(const unsigned short* __restrict__ Xp,
    const unsigned short* __restrict__ Wt, const float* __restrict__ resid,
    float* __restrict__ out){
  __shared__ unsigned short lds[24576];   // 48KB
  char* ldsb = (char*)lds;
  int tid = threadIdx.x, lane = tid & 63, w = tid >> 6;
  int col = lane & 15, kg = lane >> 4;

  int bid = blockIdx.x;
  int wgid = (bid & 7)*84 + (bid >> 3);       // bijective XCD chunking (672 = 8*84)
  int m = wgid/112; int rem = wgid - m*112;
  int b = rem/28;  int rp = rem - b*28;
  int y0 = rp*2, co0 = m*128;

  // X staging: 4 rounds x 256 thr x 16B = 16KB/buffer; linear dest, SWIZZLED source granule
  int xgo[4], xds[4];
  #pragma unroll
  for (int t = 0; t < 4; t++){
    int slot = t*256 + tid;                   // (row, px, g)
    int row = slot >> 8;
    int px  = (slot >> 2) & 63;
    int g   = slot & 3;
    int sg  = g ^ ((px >> 1) & 3);
    xgo[t] = (b*PADPIX + (y0+row)*PADW + px)*CIN + sg*8;
    xds[t] = slot*16;                         // bytes; + xb at issue
  }
  // W staging: wave w stages its own rows [w*32,w*32+32): 2 rounds; swizzled source granule
  int wgo[2], wds[2];
  #pragma unroll
  for (int j = 0; j < 2; j++){
    int r  = w*32 + j*16 + (lane>>2);
    int sg = (lane&3) ^ ((lane>>3)&3);        // ((r>>1)&3) == ((lane>>3)&3) here
    wgo[j] = (co0 + r)*CIN + sg*8;
    wds[j] = 32768 + r*64 + (lane&3)*16;      // linear in lane; + (q^1)*8192 at issue
  }
  // A-read byte offsets within a W buffer (parity added per tap)
  int awo[2];
  #pragma unroll
  for (int mf = 0; mf < 2; mf++){
    int r = w*32 + mf*16 + col;
    awo[mf] = 32768 + r*64 + ((kg ^ ((col>>1)&3)) << 4);
  }
  // B-read byte offsets (dx,nf); dy folds to +dyk*4096; xbuf via +xb
  int bb[3][7];
  #pragma unroll
  for (int nf=0; nf<7; nf++){
    int q2 = nf*16 + col;
    int qyl = (q2 >= 56) ? 1 : 0;
    int qx = q2 - 56*qyl;
    #pragma unroll
    for (int dx=0; dx<3; dx++){
      int px = qx + dx;
      bb[dx][nf] = qyl*4096 + px*64 + ((kg ^ ((px>>1)&3)) << 4);
    }
  }

  f32x4 acc[2][7];
  #pragma unroll
  for (int mf=0; mf<2; mf++)
    #pragma unroll
    for (int nf=0; nf<7; nf++)
      acc[mf][nf] = (f32x4){0.f,0.f,0.f,0.f};

  // ---- prologue: W[0] -> buf0, X[0] -> xbuf0; full drain once ----
  #pragma unroll
  for (int j = 0; j < 2; j++) gload_lds16(Wt + wgo[j], ldsb + wds[j]);
  #pragma unroll
  for (int t = 0; t < 4; t++) gload_lds16(Xp + xgo[t], ldsb + xds[t]);
  VMCNT0();
  BAR();

  int q = 0;
  for (int chunk = 0; chunk < 23; chunk++){
    const int xb = (chunk & 1) * 16384;
    #pragma unroll
    for (int kk = 0; kk < 9; kk++){
      // issue W[s+1] into W buf q^1 (wave-private rows)
      {
        int kk2 = (kk == 8) ? 0 : kk+1;
        int c2  = (kk == 8) ? chunk+1 : chunk;
        size_t gofs = (size_t)kk2*WTK + (c2 << 5);
        int dofs = (q^1)*8192;
        gload_lds16(Wt + gofs + wgo[0], ldsb + dofs + wds[0]);
        gload_lds16(Wt + gofs + wgo[1], ldsb + dofs + wds[1]);
      }
      if (kk == 6){                            // issue X[chunk+1] into other X buffer
        #pragma unroll
        for (int t = 0; t < 4; t++)
          gload_lds16(Xp + xgo[t] + (chunk+1)*32, ldsb + (xb^16384) + xds[t]);
      }
      // counted wait for W[s] (and, at kk=8, X[c+1])
      if (kk == 6 || kk == 7) VMCNT6();        // keep W[s+1] + X in flight
      else                    VMCNT2();        // kk<=5: trivial; kk==8: retires X+W[s]
      // A-frags
      const int wq = q*8192;
      bf16x8 A0 = *(const bf16x8*)(ldsb + awo[0] + wq);
      bf16x8 A1 = *(const bf16x8*)(ldsb + awo[1] + wq);
      // B-frags + MFMA
      const int dyk = kk/3, dxk = kk - dyk*3;
      const int dofs2 = xb + dyk*4096;
      __builtin_amdgcn_s_setprio(1);
      #pragma unroll
      for (int nf = 0; nf < 7; nf++){
        bf16x8 B = *(const bf16x8*)(ldsb + bb[dxk][nf] + dofs2);
        acc[0][nf] = __builtin_amdgcn_mfma_f32_16x16x32_bf16(A0, B, acc[0][nf], 0,0,0);
        acc[1][nf] = __builtin_amdgcn_mfma_f32_16x16x32_bf16(A1, B, acc[1][nf], 0,0,0);
      }
      __builtin_amdgcn_s_setprio(0);
      q ^= 1;
    }
    BAR();                                     // X[chunk+1] visible (own writes retired @kk8)
  }
  // ---- tail chunk 23 (no X issue, no trailing barrier) ----
  {
    const int xb = 16384;                      // 23&1 = 1
    #pragma unroll
    for (int kk = 0; kk < 9; kk++){
      if (kk < 8){
        size_t gofs = (size_t)(kk+1)*WTK + (23 << 5);
        int dofs = (q^1)*8192;
        gload_lds16(Wt + gofs + wgo[0], ldsb + dofs + wds[0]);
        gload_lds16(Wt + gofs + wgo[1], ldsb + dofs + wds[1]);
        VMCNT2();
      } else {
        VMCNT0();
      }
      const int wq = q*8192;
      bf16x8 A0 = *(const bf16x8*)(ldsb + awo[0] + wq);
      bf16x8 A1 = *(const bf16x8*)(ldsb + awo[1] + wq);
      const int dyk = kk/3, dxk = kk - dyk*3;
      const int dofs2 = xb + dyk*4096;
      __builtin_amdgcn_s_setprio(1);
      #pragma unroll
      for (int nf = 0; nf < 7; nf++){
        bf16x8 B = *(const bf16x8*)(ldsb + bb[dxk][nf] + dofs2);
        acc[0][nf] = __builtin_amdgcn_mfma_f32_16x16x32_bf16(A0, B, acc[0][nf], 0,0,0);
        acc[1][nf] = __builtin_amdgcn_mfma_f32_16x16x32_bf16(A1, B, acc[1][nf], 0,0,0);
      }
      __builtin_amdgcn_s_setprio(0);
      q ^= 1;
    }
  }

  // ---- epilogue: NCGHW fp32 (+residual) ----
  #pragma unroll
  for (int mf = 0; mf < 2; mf++){
    int co_b = co0 + w*32 + mf*16;            // 16-aligned; never straddles h (96%16==0)
    int h = co_b/C96;
    int ob = co_b - h*C96 + kg*4;
    #pragma unroll
    for (int nf = 0; nf < 7; nf++){
      int qq = nf*16 + col;
      #pragma unroll
      for (int r = 0; r < 4; r++){
        size_t oi = ((size_t)((b*C96 + ob + r)*8 + h))*PIX + y0*56 + qq;
        float v = acc[mf][nf][r];
        if (resid) v += resid[oi];
        out[oi] = v;
      }
    }
  }
}

// ---------- host side ----------
static void run_layer(const float* bn_in,
                      const float* a1W, const float* a2W, const float* spW,
                      const float* bng, const float* bnb,
                      const float* resid, float* convout,
                      float* spart, float* sbuf, float* ach, float* ppP, float* aspt,
                      unsigned short* Wt, unsigned short* Xp, hipStream_t stream)
{
  k_bn_stats<<<dim3(C96,8),256,0,stream>>>(bn_in, spart);
  k_pool<<<dim3(13,32),256,0,stream>>>(bn_in, spart, bng, bnb, ppP);
  k_chan<<<4*C96*NG,64,0,stream>>>(bn_in, spart, bng, bnb, sbuf);
  k_ca<<<4,CIN,0,stream>>>(sbuf, a1W, a2W, ach);
  k_sp_conv<<<dim3(13,32),256,0,stream>>>(ppP, spW, aspt);
  k_mod_t<<<dim3(PIX/64, CIN/64, 4),256,0,stream>>>(bn_in, spart, bng, bnb, ach, aspt, (unsigned int*)Xp);
  k_convmf<<<672,256,0,stream>>>(Xp, Wt, resid, convout);
}

extern "C" void kernel_launch(void* const* d_in, const int* in_sizes, int n_in,
                              void* d_out, int out_size, void* d_ws, size_t ws_size,
                              hipStream_t stream) {
  const float* x    = (const float*)d_in[0];
  const float* bn1g = (const float*)d_in[1];
  const float* bn1b = (const float*)d_in[2];
  const float* bn2g = (const float*)d_in[3];
  const float* bn2b = (const float*)d_in[4];
  const float* c1W  = (const float*)d_in[5];
  const float* c1a1 = (const float*)d_in[6];
  const float* c1a2 = (const float*)d_in[7];
  const float* c1sp = (const float*)d_in[8];
  const float* c2W  = (const float*)d_in[9];
  const float* c2a1 = (const float*)d_in[10];
  const float* c2a2 = (const float*)d_in[11];
  const float* c2sp = (const float*)d_in[12];
  float* out = (float*)d_out;
  float* ws  = (float*)d_ws;

  float* bufA = ws;                                          // 9,633,792 f32
  unsigned short* Wt1 = (unsigned short*)(bufA + NPIXT);     // 5,308,416 bf16
  unsigned short* Wt2 = Wt1 + 9*CIN*CIN;                     // 5,308,416 bf16
  unsigned short* Xp  = Wt2 + 9*CIN*CIN;                     // 10,334,208 bf16
  float* spart = (float*)(Xp + (size_t)4*PADPIX*CIN);        // 1536
  float* sbuf  = spart + 1536;                               // 3072
  float* ach   = sbuf + 4*C96*NG;                            // 3072
  float* ppP   = ach + 4*C96*NG;                             // 253,952 (padded pool)
  float* aspt  = ppP + 4*16*PPL;                             // 100,352
  // total ~= 83 MB

  k_ktb2<<<dim3((9*CIN*CIN)/256, 2),256,0,stream>>>(c1W, c2W, Wt1, Wt2);
  k_zerob<<<590,256,0,stream>>>((uint4*)Xp, (uint4*)ppP);

  // layer 1: bufA = conv_gg(mod(relu(bn1(x))))
  run_layer(x, c1a1, c1a2, c1sp, bn1g, bn1b, nullptr, bufA,
            spart, sbuf, ach, ppP, aspt, Wt1, Xp, stream);
  // layer 2: out = x + conv_gg(mod(relu(bn2(bufA))))
  run_layer(bufA, c2a1, c2a2, c2sp, bn2g, bn2b, x, out,
            spart, sbuf, ach, ppP, aspt, Wt2, Xp, stream);
}

// Round 15
// 447.593 us; speedup vs baseline: 1.2158x; 1.0531x over previous
//
#include <hip/hip_runtime.h>
#include <math.h>

#define NG 8
#define C96 96
#define NMID 48
#define HW 56
#define PIX 3136      // 56*56
#define GHW 25088     // 8*3136
#define CIN 768       // 96*8
#define NPIXT 9633792 // 4*96*8*3136
#define BN_N 100352   // 4*8*3136
#define PADW 58
#define PADPIX 3364   // 58*58
#define WTK 589824    // 768*768 per-tap stride in Wt
#define PPL 3968      // padded pool plane: 62 rows x 64 cols

typedef __attribute__((ext_vector_type(8))) short bf16x8;
typedef __attribute__((ext_vector_type(4))) float f32x4;

// ---------- group math (verified rounds 0-14) ----------
__device__ __forceinline__ int d_comp(int a, int b){
  int m1=a>>2, r1=a&3, m2=b>>2, r2=b&3;
  int m=(m1+m2)&1;
  int r = (m2==0) ? (r1+r2) : (r2-r1);
  r = (r+4)&3;
  return 4*m+r;
}
__device__ __forceinline__ int d_inv(int a){ return (a>>2) ? a : ((4-(a&3))&3); }
__device__ __forceinline__ int d_perm(int h, int g){ return d_comp(d_inv(h), g); }

__device__ __forceinline__ void d_src(int h, int dy, int dx, int n, int* sy, int* sx){
  int r=h&3, m=h>>2, e=n-1;
  int y,x;
  if(r==0){y=dy; x=dx;}
  else if(r==1){y=dx; x=e-dy;}
  else if(r==2){y=e-dy; x=e-dx;}
  else {y=e-dx; x=dy;}
  if(m) x = e-x;
  *sy=y; *sx=x;
}

__device__ __forceinline__ unsigned short f2bf(float f){
  unsigned int u = __builtin_bit_cast(unsigned int, f);
  unsigned int r = (u + 0x7FFFu + ((u>>16)&1u)) >> 16;
  return (unsigned short)r;
}

__device__ __forceinline__ void gload_lds16(const void* g, void* l){
  __builtin_amdgcn_global_load_lds((const __attribute__((address_space(1))) unsigned int*)g,
                                   (__attribute__((address_space(3))) unsigned int*)l, 16, 0, 0);
}

#define VMCNT6() do { asm volatile("s_waitcnt vmcnt(6)" ::: "memory"); \
                      __builtin_amdgcn_sched_barrier(0); } while(0)
#define VMCNT2() do { asm volatile("s_waitcnt vmcnt(2)" ::: "memory"); \
                      __builtin_amdgcn_sched_barrier(0); } while(0)
#define VMCNT0() do { asm volatile("s_waitcnt vmcnt(0)" ::: "memory"); \
                      __builtin_amdgcn_sched_barrier(0); } while(0)
#define BAR() do { __builtin_amdgcn_s_barrier(); __builtin_amdgcn_sched_barrier(0); } while(0)

// ---------- BN partial stats (kept for layer 2): grid (96, 8) ----------
__global__ void k_bn_stats(const float* __restrict__ in, float* __restrict__ spart){
  __shared__ float sm[8];
  int c = blockIdx.x, s = blockIdx.y;
  int b = s>>1, half = s&1;
  const float4* p = (const float4*)(in + ((size_t)(b*C96 + c))*GHW) + half*(GHW/8);
  float sum=0.f, sum2=0.f;
  for (int i=threadIdx.x; i<GHW/8; i+=256){
    float4 v = p[i];
    sum  += v.x+v.y+v.z+v.w;
    sum2 += v.x*v.x+v.y*v.y+v.z*v.z+v.w*v.w;
  }
  #pragma unroll
  for (int off=32; off>0; off>>=1){ sum += __shfl_down(sum,off); sum2 += __shfl_down(sum2,off); }
  int lane=threadIdx.x&63, wid=threadIdx.x>>6;
  if(lane==0){ sm[wid]=sum; sm[4+wid]=sum2; }
  __syncthreads();
  if(threadIdx.x==0){
    float a=sm[0]+sm[1]+sm[2]+sm[3], b2=sm[4]+sm[5]+sm[6]+sm[7];
    spart[(c*8+s)*2]   = a;
    spart[(c*8+s)*2+1] = b2;
  }
}

// ---------- k_prep: role-split {ktb2 | zerob | bn_stats(x)} in one launch ----------
// blocks [0,41472): weight transform (both layers); [41472,42062): zero pool+Xp borders;
// [42062,42830): bn partial stats of x (layer 1).
__global__ __launch_bounds__(256) void k_prep(const float* __restrict__ W1src,
    const float* __restrict__ W2src, unsigned short* __restrict__ Wt1,
    unsigned short* __restrict__ Wt2, uint4* __restrict__ xp, uint4* __restrict__ ppz,
    const float* __restrict__ xin, float* __restrict__ spart){
  __shared__ float sm[8];
  int bid = blockIdx.x, tid = threadIdx.x;
  if (bid < 41472){
    const float* W = (bid >= 20736) ? W2src : W1src;
    unsigned short* Wt = (bid >= 20736) ? Wt2 : Wt1;
    int bx = (bid >= 20736) ? bid - 20736 : bid;
    int idx = bx*256 + tid;
    int ci = idx % CIN;
    int t2 = idx / CIN;
    int co = t2 % CIN;
    int kk = t2 / CIN;
    int h = co/C96, o = co - h*C96;
    int i = ci >> 3, g = ci & 7;
    int dy = kk/3, dx = kk - dy*3;
    int sy, sx; d_src(h, dy, dx, 3, &sy, &sx);
    float v = W[((o*C96 + i)*8 + d_perm(h,g))*9 + sy*3 + sx];
    Wt[idx] = f2bf(v);
  } else if (bid < 42062){
    int zb = bid - 41472;
    uint4 z = (uint4){0u,0u,0u,0u};
    int i = zb*256 + tid;
    if (zb < 248){ ppz[i] = z; return; }               // 248*256 = 63488 = 4*16*PPL/4
    int r = i - 63488;
    if (r >= 87552) return;                             // 4b * 228 border px * 96 uint4
    int b = r / 21888;
    int q = r - b*21888;
    int p = q / 96, j = q - p*96;
    int y, x;
    if (p < 58){ y=0; x=p; }
    else if (p < 116){ y=57; x=p-58; }
    else if (p < 172){ y=p-115; x=0; }
    else { y=p-171; x=57; }
    xp[(size_t)(b*PADPIX + y*PADW + x)*96 + j] = z;
  } else {
    int sb = bid - 42062;                               // [0,768)
    int c = sb % C96, s = sb / C96;
    int b = s>>1, half = s&1;
    const float4* p = (const float4*)(xin + ((size_t)(b*C96 + c))*GHW) + half*(GHW/8);
    float sum=0.f, sum2=0.f;
    for (int i=tid; i<GHW/8; i+=256){
      float4 v = p[i];
      sum  += v.x+v.y+v.z+v.w;
      sum2 += v.x*v.x+v.y*v.y+v.z*v.z+v.w*v.w;
    }
    #pragma unroll
    for (int off=32; off>0; off>>=1){ sum += __shfl_down(sum,off); sum2 += __shfl_down(sum2,off); }
    int lane=tid&63, wid=tid>>6;
    if(lane==0){ sm[wid]=sum; sm[4+wid]=sum2; }
    __syncthreads();
    if(tid==0){
      float a=sm[0]+sm[1]+sm[2]+sm[3], b2=sm[4]+sm[5]+sm[6]+sm[7];
      spart[(c*8+s)*2]   = a;
      spart[(c*8+s)*2+1] = b2;
    }
  }
}

// ---------- k_poolchan: role-split {spatial pool | channel means}, one read graph ----------
// blocks [0,416): pool (x strip = bid%13, bg = bid/13); [416,1184): chan, 4 bcg/block (1/wave).
__global__ __launch_bounds__(256) void k_poolchan(const float* __restrict__ in,
    const float* __restrict__ spart, const float* __restrict__ gamma, const float* __restrict__ beta,
    float* __restrict__ pp, float* __restrict__ sout){
  __shared__ float scs[C96], shs[C96];
  int bid = blockIdx.x, tid = threadIdx.x;
  if (bid < 416){
    if (tid < C96){
      float s=0.f, s2=0.f;
      #pragma unroll
      for (int k=0;k<8;k++){ s += spart[(tid*8+k)*2]; s2 += spart[(tid*8+k)*2+1]; }
      float mean = s*(1.f/BN_N);
      float var  = s2*(1.f/BN_N) - mean*mean;
      float sc = gamma[tid]*rsqrtf(var + 2e-5f);
      scs[tid] = sc; shs[tid] = beta[tid] - mean*sc;
    }
    __syncthreads();
    int bg = bid / 13; int b = bg>>3, g = bg&7;
    int px = (bid % 13)*256 + tid;
    if (px >= PIX) return;
    float pm0=0.f, pm1=0.f, mx0=0.f, mx1=0.f;
    for (int c = 0; c < C96; c += 2){
      size_t i0 = ((size_t)((b*C96 + c)*8 + g))*PIX + px;
      size_t i1 = i0 + (size_t)8*PIX;
      float v0 = fmaxf(fmaf(in[i0], scs[c],   shs[c]),   0.f);
      float v1 = fmaxf(fmaf(in[i1], scs[c+1], shs[c+1]), 0.f);
      pm0 += v0; mx0 = fmaxf(mx0, v0);
      pm1 += v1; mx1 = fmaxf(mx1, v1);
    }
    int y = px/HW, x = px - y*HW;
    pp[(size_t)(b*16 + g)*PPL     + (y+3)*64 + (x+3)] = pm0+pm1;
    pp[(size_t)(b*16 + 8 + g)*PPL + (y+3)*64 + (x+3)] = fmaxf(mx0,mx1);
  } else {
    int lane = tid & 63, wid = tid >> 6;
    int bcg = (bid - 416)*4 + wid;                      // [0,3072)
    int c = (bcg >> 3) % C96;
    float s=0.f, s2=0.f;
    #pragma unroll
    for (int k=0;k<8;k++){ s += spart[(c*8+k)*2]; s2 += spart[(c*8+k)*2+1]; }
    float mean = s*(1.f/BN_N);
    float var  = s2*(1.f/BN_N) - mean*mean;
    float sc = gamma[c]*rsqrtf(var + 2e-5f);
    float sh = beta[c] - mean*sc;
    const float4* p = (const float4*)(in + (size_t)bcg*PIX);
    float acc=0.f;
    for (int i=lane; i<PIX/4; i+=64){
      float4 v = p[i];
      acc += fmaxf(fmaf(v.x,sc,sh),0.f) + fmaxf(fmaf(v.y,sc,sh),0.f)
           + fmaxf(fmaf(v.z,sc,sh),0.f) + fmaxf(fmaf(v.w,sc,sh),0.f);
    }
    #pragma unroll
    for(int off=32;off>0;off>>=1) acc += __shfl_down(acc,off);
    if(lane==0) sout[bcg] = acc * (1.f/3136.f);
  }
}

// ---------- k_casp: role-split {channel attention | spatial attention conv} ----------
// blocks [0,4): ca (b=bid, 256 thr grid-stride); [4,420): sp_conv (flattened (13,32)).
__global__ __launch_bounds__(256) void k_casp(const float* __restrict__ sbuf,
    const float* __restrict__ W1, const float* __restrict__ W2,
    const float* __restrict__ pp, const float* __restrict__ Wsp,
    float* __restrict__ ach, float* __restrict__ aspt){
  __shared__ float shm[1280];        // ca: sl[768]+tl[384]; sp: wl[784]
  int bid = blockIdx.x, tid = threadIdx.x;
  if (bid < 4){
    float* sl = shm; float* tl = shm + 768;
    int b = bid;
    for (int t = tid; t < CIN; t += 256) sl[t] = sbuf[b*CIN + t];
    __syncthreads();
    int o = tid & 7;                  // invariant across t (256 % 8 == 0)
    int pg[8];
    #pragma unroll
    for (int g=0; g<8; g++) pg[g] = d_perm(o, g);
    for (int t = tid; t < NMID*8; t += 256){
      int m = t >> 3;
      float a0 = 0.f, a1 = 0.f;
      for (int c=0; c<C96; c+=2){
        #pragma unroll
        for (int g=0; g<8; g++) a0 += W1[(m*C96+c)*8+pg[g]] * sl[c*8+g];
        #pragma unroll
        for (int g=0; g<8; g++) a1 += W1[(m*C96+c+1)*8+pg[g]] * sl[(c+1)*8+g];
      }
      tl[t] = fmaxf(a0+a1, 0.f);
    }
    __syncthreads();
    for (int t = tid; t < CIN; t += 256){
      int c = t >> 3;
      float a0 = 0.f, a1 = 0.f;
      for (int m=0; m<NMID; m+=2){
        #pragma unroll
        for (int g=0; g<8; g++) a0 += W2[(c*NMID+m)*8+pg[g]] * tl[(m<<3)+g];
        #pragma unroll
        for (int g=0; g<8; g++) a1 += W2[(c*NMID+m+1)*8+pg[g]] * tl[((m+1)<<3)+g];
      }
      ach[b*CIN + t] = 1.f/(1.f+__expf(-(a0+a1)));
    }
  } else {
    float* wl = shm;
    int bid2 = bid - 4;
    int xs = bid2 % 13, bh = bid2 / 13;
    int b = bh>>3, h = bh&7;
    for(int idx=tid; idx<784; idx+=256){
      int i = idx/392; int rem = idx-i*392;
      int g = rem/49; int kk = rem-g*49;
      int dy=kk/7, dx=kk-dy*7;
      int pg = d_perm(h,g);
      int sy,sx; d_src(h,dy,dx,7,&sy,&sx);
      wl[idx] = Wsp[(i*8+pg)*49 + sy*7+sx] * (i==0 ? (1.f/96.f) : 1.f);
    }
    __syncthreads();
    int pix = xs*256 + tid;
    if(pix>=PIX) return;
    int y=pix/HW, x=pix-y*HW;
    const float* base = pp + (size_t)(b*16)*PPL + y*64 + x;
    float ac[4] = {0.f,0.f,0.f,0.f};
    #pragma unroll
    for(int ig=0; ig<16; ig++){
      const float* pb = base + (size_t)ig*PPL;
      const float* wb = wl + ig*49;
      #pragma unroll
      for(int dy=0; dy<7; dy++){
        #pragma unroll
        for(int dx=0; dx<7; dx++)
          ac[ig&3] = fmaf(pb[dy*64+dx], wb[dy*7+dx], ac[ig&3]);
      }
    }
    float acc = (ac[0]+ac[1]) + (ac[2]+ac[3]);
    aspt[((size_t)b*PIX + pix)*8 + h] = 1.f/(1.f+__expf(-acc));
  }
}

// ---------- fused bn+relu + modulate + transpose + bf16 pack ----------
__global__ __launch_bounds__(256) void k_mod_t(const float* __restrict__ in,
    const float* __restrict__ spart, const float* __restrict__ gamma, const float* __restrict__ beta,
    const float* __restrict__ ach, const float* __restrict__ aspt,
    unsigned int* __restrict__ XpU){
  __shared__ float tile[64][65];
  __shared__ float scs8[8], shs8[8];
  int b = blockIdx.z;
  int cg0 = blockIdx.y*64;
  int pix0 = blockIdx.x*64;
  int tid = threadIdx.x;
  if (tid < 8){
    int c = (cg0>>3) + tid;
    float s=0.f, s2=0.f;
    #pragma unroll
    for (int k=0;k<8;k++){ s += spart[(c*8+k)*2]; s2 += spart[(c*8+k)*2+1]; }
    float mean = s*(1.f/BN_N);
    float var  = s2*(1.f/BN_N) - mean*mean;
    float sc = gamma[c]*rsqrtf(var + 2e-5f);
    scs8[tid] = sc; shs8[tid] = beta[c] - mean*sc;
  }
  __syncthreads();
  int lane = tid & 63, w = tid >> 6;
  for (int r = w; r < 64; r += 4){
    int cg = cg0 + r;
    float a1 = ach[b*CIN + cg];
    float raw = in[(size_t)(b*CIN + cg)*PIX + pix0 + lane];
    float v = fmaxf(fmaf(raw, scs8[r>>3], shs8[r>>3]), 0.f);
    tile[r][lane] = v * a1;
  }
  __syncthreads();
  int half = lane >> 5;
  int cgA = (lane & 31)*2;
  #pragma unroll
  for (int it = 0; it < 8; it++){
    int p = it*8 + w*2 + half;
    int pix = pix0 + p;
    int y = pix/HW, x = pix - y*HW;
    float2 a2 = *(const float2*)(aspt + ((size_t)b*PIX + pix)*8 + (cgA&7));
    float vA = tile[cgA][p]   * a2.x;
    float vB = tile[cgA+1][p] * a2.y;
    unsigned int u = (unsigned int)f2bf(vA) | ((unsigned int)f2bf(vB) << 16);
    XpU[(((size_t)b*PADPIX + (y+1)*PADW + (x+1))*CIN + cg0 + cgA) >> 1] = u;
  }
}

// ---------- main conv: round-12/14 config (verified 147-149us, MfmaUtil 39%) ----------
// BM=128, K-chunk=32, 256 thr (4 waves, wave 32co x 112px). Grid 672 = 8x84 XCD-chunked.
// LDS 48KB: X dbuf 2x16KB [0,32K) + W dbuf 2x8KB [32K,48K).
// Bank swizzle g' = kg ^ ((px>>1)&3) on global SOURCE + reads (verified: conflicts=0).
// Wave w stages+reads only W rows [w*32,w*32+32) -> per-wave counted vmcnt, no W barrier.
// X[c+1] issued at kk=6; waits: kk<=5:(2), kk6,7:(6), kk8:(2); ONE barrier per chunk.
__global__ __launch_bounds__(256, 3) void k_convmf(const unsigned short* __restrict__ Xp,
    const unsigned short* __restrict__ Wt, const float* __restrict__ resid,
    float* __restrict__ out){
  __shared__ unsigned short lds[24576];   // 48KB
  char* ldsb = (char*)lds;
  int tid = threadIdx.x, lane = tid & 63, w = tid >> 6;
  int col = lane & 15, kg = lane >> 4;

  int bid = blockIdx.x;
  int wgid = (bid & 7)*84 + (bid >> 3);       // bijective XCD chunking (672 = 8*84)
  int m = wgid/112; int rem = wgid - m*112;
  int b = rem/28;  int rp = rem - b*28;
  int y0 = rp*2, co0 = m*128;

  int xgo[4], xds[4];
  #pragma unroll
  for (int t = 0; t < 4; t++){
    int slot = t*256 + tid;                   // (row, px, g)
    int row = slot >> 8;
    int px  = (slot >> 2) & 63;
    int g   = slot & 3;
    int sg  = g ^ ((px >> 1) & 3);
    xgo[t] = (b*PADPIX + (y0+row)*PADW + px)*CIN + sg*8;
    xds[t] = slot*16;                         // bytes; + xb at issue
  }
  int wgo[2], wds[2];
  #pragma unroll
  for (int j = 0; j < 2; j++){
    int r  = w*32 + j*16 + (lane>>2);
    int sg = (lane&3) ^ ((lane>>3)&3);
    wgo[j] = (co0 + r)*CIN + sg*8;
    wds[j] = 32768 + r*64 + (lane&3)*16;
  }
  int awo[2];
  #pragma unroll
  for (int mf = 0; mf < 2; mf++){
    int r = w*32 + mf*16 + col;
    awo[mf] = 32768 + r*64 + ((kg ^ ((col>>1)&3)) << 4);
  }
  int bb[3][7];
  #pragma unroll
  for (int nf=0; nf<7; nf++){
    int q2 = nf*16 + col;
    int qyl = (q2 >= 56) ? 1 : 0;
    int qx = q2 - 56*qyl;
    #pragma unroll
    for (int dx=0; dx<3; dx++){
      int px = qx + dx;
      bb[dx][nf] = qyl*4096 + px*64 + ((kg ^ ((px>>1)&3)) << 4);
    }
  }

  f32x4 acc[2][7];
  #pragma unroll
  for (int mf=0; mf<2; mf++)
    #pragma unroll
    for (int nf=0; nf<7; nf++)
      acc[mf][nf] = (f32x4){0.f,0.f,0.f,0.f};

  #pragma unroll
  for (int j = 0; j < 2; j++) gload_lds16(Wt + wgo[j], ldsb + wds[j]);
  #pragma unroll
  for (int t = 0; t < 4; t++) gload_lds16(Xp + xgo[t], ldsb + xds[t]);
  VMCNT0();
  BAR();

  int q = 0;
  for (int chunk = 0; chunk < 23; chunk++){
    const int xb = (chunk & 1) * 16384;
    #pragma unroll
    for (int kk = 0; kk < 9; kk++){
      {
        int kk2 = (kk == 8) ? 0 : kk+1;
        int c2  = (kk == 8) ? chunk+1 : chunk;
        size_t gofs = (size_t)kk2*WTK + (c2 << 5);
        int dofs = (q^1)*8192;
        gload_lds16(Wt + gofs + wgo[0], ldsb + dofs + wds[0]);
        gload_lds16(Wt + gofs + wgo[1], ldsb + dofs + wds[1]);
      }
      if (kk == 6){
        #pragma unroll
        for (int t = 0; t < 4; t++)
          gload_lds16(Xp + xgo[t] + (chunk+1)*32, ldsb + (xb^16384) + xds[t]);
      }
      if (kk == 6 || kk == 7) VMCNT6();
      else                    VMCNT2();
      const int wq = q*8192;
      bf16x8 A0 = *(const bf16x8*)(ldsb + awo[0] + wq);
      bf16x8 A1 = *(const bf16x8*)(ldsb + awo[1] + wq);
      const int dyk = kk/3, dxk = kk - dyk*3;
      const int dofs2 = xb + dyk*4096;
      __builtin_amdgcn_s_setprio(1);
      #pragma unroll
      for (int nf = 0; nf < 7; nf++){
        bf16x8 B = *(const bf16x8*)(ldsb + bb[dxk][nf] + dofs2);
        acc[0][nf] = __builtin_amdgcn_mfma_f32_16x16x32_bf16(A0, B, acc[0][nf], 0,0,0);
        acc[1][nf] = __builtin_amdgcn_mfma_f32_16x16x32_bf16(A1, B, acc[1][nf], 0,0,0);
      }
      __builtin_amdgcn_s_setprio(0);
      q ^= 1;
    }
    BAR();
  }
  {
    const int xb = 16384;
    #pragma unroll
    for (int kk = 0; kk < 9; kk++){
      if (kk < 8){
        size_t gofs = (size_t)(kk+1)*WTK + (23 << 5);
        int dofs = (q^1)*8192;
        gload_lds16(Wt + gofs + wgo[0], ldsb + dofs + wds[0]);
        gload_lds16(Wt + gofs + wgo[1], ldsb + dofs + wds[1]);
        VMCNT2();
      } else {
        VMCNT0();
      }
      const int wq = q*8192;
      bf16x8 A0 = *(const bf16x8*)(ldsb + awo[0] + wq);
      bf16x8 A1 = *(const bf16x8*)(ldsb + awo[1] + wq);
      const int dyk = kk/3, dxk = kk - dyk*3;
      const int dofs2 = xb + dyk*4096;
      __builtin_amdgcn_s_setprio(1);
      #pragma unroll
      for (int nf = 0; nf < 7; nf++){
        bf16x8 B = *(const bf16x8*)(ldsb + bb[dxk][nf] + dofs2);
        acc[0][nf] = __builtin_amdgcn_mfma_f32_16x16x32_bf16(A0, B, acc[0][nf], 0,0,0);
        acc[1][nf] = __builtin_amdgcn_mfma_f32_16x16x32_bf16(A1, B, acc[1][nf], 0,0,0);
      }
      __builtin_amdgcn_s_setprio(0);
      q ^= 1;
    }
  }

  #pragma unroll
  for (int mf = 0; mf < 2; mf++){
    int co_b = co0 + w*32 + mf*16;
    int h = co_b/C96;
    int ob = co_b - h*C96 + kg*4;
    #pragma unroll
    for (int nf = 0; nf < 7; nf++){
      int qq = nf*16 + col;
      #pragma unroll
      for (int r = 0; r < 4; r++){
        size_t oi = ((size_t)((b*C96 + ob + r)*8 + h))*PIX + y0*56 + qq;
        float v = acc[mf][nf][r];
        if (resid) v += resid[oi];
        out[oi] = v;
      }
    }
  }
}

// ---------- host side ----------
static void run_layer(const float* bn_in,
                      const float* a1W, const float* a2W, const float* spW,
                      const float* bng, const float* bnb,
                      const float* resid, float* convout,
                      float* spart, float* sbuf, float* ach, float* ppP, float* aspt,
                      unsigned short* Wt, unsigned short* Xp, hipStream_t stream)
{
  k_poolchan<<<1184,256,0,stream>>>(bn_in, spart, bng, bnb, ppP, sbuf);
  k_casp<<<420,256,0,stream>>>(sbuf, a1W, a2W, ppP, spW, ach, aspt);
  k_mod_t<<<dim3(PIX/64, CIN/64, 4),256,0,stream>>>(bn_in, spart, bng, bnb, ach, aspt, (unsigned int*)Xp);
  k_convmf<<<672,256,0,stream>>>(Xp, Wt, resid, convout);
}

extern "C" void kernel_launch(void* const* d_in, const int* in_sizes, int n_in,
                              void* d_out, int out_size, void* d_ws, size_t ws_size,
                              hipStream_t stream) {
  const float* x    = (const float*)d_in[0];
  const float* bn1g = (const float*)d_in[1];
  const float* bn1b = (const float*)d_in[2];
  const float* bn2g = (const float*)d_in[3];
  const float* bn2b = (const float*)d_in[4];
  const float* c1W  = (const float*)d_in[5];
  const float* c1a1 = (const float*)d_in[6];
  const float* c1a2 = (const float*)d_in[7];
  const float* c1sp = (const float*)d_in[8];
  const float* c2W  = (const float*)d_in[9];
  const float* c2a1 = (const float*)d_in[10];
  const float* c2a2 = (const float*)d_in[11];
  const float* c2sp = (const float*)d_in[12];
  float* out = (float*)d_out;
  float* ws  = (float*)d_ws;

  float* bufA = ws;                                          // 9,633,792 f32
  unsigned short* Wt1 = (unsigned short*)(bufA + NPIXT);     // 5,308,416 bf16
  unsigned short* Wt2 = Wt1 + 9*CIN*CIN;                     // 5,308,416 bf16
  unsigned short* Xp  = Wt2 + 9*CIN*CIN;                     // 10,334,208 bf16
  float* spart = (float*)(Xp + (size_t)4*PADPIX*CIN);        // 1536
  float* sbuf  = spart + 1536;                               // 3072
  float* ach   = sbuf + 4*C96*NG;                            // 3072
  float* ppP   = ach + 4*C96*NG;                             // 253,952 (padded pool)
  float* aspt  = ppP + 4*16*PPL;                             // 100,352
  // total ~= 83 MB

  // one launch: weight transforms + border zero + layer-1 bn stats (all independent)
  k_prep<<<42830,256,0,stream>>>(c1W, c2W, Wt1, Wt2, (uint4*)Xp, (uint4*)ppP, x, spart);

  // layer 1: bufA = conv_gg(mod(relu(bn1(x))))
  run_layer(x, c1a1, c1a2, c1sp, bn1g, bn1b, nullptr, bufA,
            spart, sbuf, ach, ppP, aspt, Wt1, Xp, stream);
  // layer 2: out = x + conv_gg(mod(relu(bn2(bufA))))
  k_bn_stats<<<dim3(C96,8),256,0,stream>>>(bufA, spart);
  run_layer(bufA, c2a1, c2a2, c2sp, bn2g, bn2b, x, out,
            spart, sbuf, ach, ppP, aspt, Wt2, Xp, stream);
}

// Round 17
// 447.546 us; speedup vs baseline: 1.2159x; 1.0001x over previous
//
#include <hip/hip_runtime.h>
#include <math.h>

#define NG 8
#define C96 96
#define NMID 48
#define HW 56
#define PIX 3136      // 56*56
#define GHW 25088     // 8*3136
#define CIN 768       // 96*8
#define NPIXT 9633792 // 4*96*8*3136
#define BN_N 100352   // 4*8*3136
#define PADW 58
#define PADPIX 3364   // 58*58
#define WTK 589824    // 768*768 per-tap stride in Wt
#define PPL 3968      // padded pool plane: 62 rows x 64 cols

typedef __attribute__((ext_vector_type(8))) short bf16x8;
typedef __attribute__((ext_vector_type(4))) float f32x4;

// ---------- group math (verified rounds 0-16) ----------
__device__ __forceinline__ int d_comp(int a, int b){
  int m1=a>>2, r1=a&3, m2=b>>2, r2=b&3;
  int m=(m1+m2)&1;
  int r = (m2==0) ? (r1+r2) : (r2-r1);
  r = (r+4)&3;
  return 4*m+r;
}
__device__ __forceinline__ int d_inv(int a){ return (a>>2) ? a : ((4-(a&3))&3); }
__device__ __forceinline__ int d_perm(int h, int g){ return d_comp(d_inv(h), g); }

__device__ __forceinline__ void d_src(int h, int dy, int dx, int n, int* sy, int* sx){
  int r=h&3, m=h>>2, e=n-1;
  int y,x;
  if(r==0){y=dy; x=dx;}
  else if(r==1){y=dx; x=e-dy;}
  else if(r==2){y=e-dy; x=e-dx;}
  else {y=e-dx; x=dy;}
  if(m) x = e-x;
  *sy=y; *sx=x;
}

__device__ __forceinline__ unsigned short f2bf(float f){
  unsigned int u = __builtin_bit_cast(unsigned int, f);
  unsigned int r = (u + 0x7FFFu + ((u>>16)&1u)) >> 16;
  return (unsigned short)r;
}

__device__ __forceinline__ void gload_lds16(const void* g, void* l){
  __builtin_amdgcn_global_load_lds((const __attribute__((address_space(1))) unsigned int*)g,
                                   (__attribute__((address_space(3))) unsigned int*)l, 16, 0, 0);
}

#define VMCNT6() do { asm volatile("s_waitcnt vmcnt(6)" ::: "memory"); \
                      __builtin_amdgcn_sched_barrier(0); } while(0)
#define VMCNT2() do { asm volatile("s_waitcnt vmcnt(2)" ::: "memory"); \
                      __builtin_amdgcn_sched_barrier(0); } while(0)
#define VMCNT0() do { asm volatile("s_waitcnt vmcnt(0)" ::: "memory"); \
                      __builtin_amdgcn_sched_barrier(0); } while(0)
#define BAR() do { __builtin_amdgcn_s_barrier(); __builtin_amdgcn_sched_barrier(0); } while(0)

// ---------- BN partial stats (layer 2): grid (96, 8) — deterministic, no atomics ----------
__global__ void k_bn_stats(const float* __restrict__ in, float* __restrict__ spart){
  __shared__ float sm[8];
  int c = blockIdx.x, s = blockIdx.y;
  int b = s>>1, half = s&1;
  const float4* p = (const float4*)(in + ((size_t)(b*C96 + c))*GHW) + half*(GHW/8);
  float sum=0.f, sum2=0.f;
  for (int i=threadIdx.x; i<GHW/8; i+=256){
    float4 v = p[i];
    sum  += v.x+v.y+v.z+v.w;
    sum2 += v.x*v.x+v.y*v.y+v.z*v.z+v.w*v.w;
  }
  #pragma unroll
  for (int off=32; off>0; off>>=1){ sum += __shfl_down(sum,off); sum2 += __shfl_down(sum2,off); }
  int lane=threadIdx.x&63, wid=threadIdx.x>>6;
  if(lane==0){ sm[wid]=sum; sm[4+wid]=sum2; }
  __syncthreads();
  if(threadIdx.x==0){
    float a=sm[0]+sm[1]+sm[2]+sm[3], b2=sm[4]+sm[5]+sm[6]+sm[7];
    spart[(c*8+s)*2]   = a;
    spart[(c*8+s)*2+1] = b2;
  }
}

// ---------- k_prep: role-split {ktb2 | zerob | bn_stats(x)} in one launch ----------
// blocks [0,41472): weight transform (both layers); [41472,42062): zero pool+Xp borders;
// [42062,42830): bn partial stats of x (layer 1).
__global__ __launch_bounds__(256) void k_prep(const float* __restrict__ W1src,
    const float* __restrict__ W2src, unsigned short* __restrict__ Wt1,
    unsigned short* __restrict__ Wt2, uint4* __restrict__ xp, uint4* __restrict__ ppz,
    const float* __restrict__ xin, float* __restrict__ spart){
  __shared__ float sm[8];
  int bid = blockIdx.x, tid = threadIdx.x;
  if (bid < 41472){
    const float* W = (bid >= 20736) ? W2src : W1src;
    unsigned short* Wt = (bid >= 20736) ? Wt2 : Wt1;
    int bx = (bid >= 20736) ? bid - 20736 : bid;
    int idx = bx*256 + tid;
    int ci = idx % CIN;
    int t2 = idx / CIN;
    int co = t2 % CIN;
    int kk = t2 / CIN;
    int h = co/C96, o = co - h*C96;
    int i = ci >> 3, g = ci & 7;
    int dy = kk/3, dx = kk - dy*3;
    int sy, sx; d_src(h, dy, dx, 3, &sy, &sx);
    float v = W[((o*C96 + i)*8 + d_perm(h,g))*9 + sy*3 + sx];
    Wt[idx] = f2bf(v);
  } else if (bid < 42062){
    int zb = bid - 41472;
    uint4 z = (uint4){0u,0u,0u,0u};
    int i = zb*256 + tid;
    if (zb < 248){ ppz[i] = z; return; }               // 248*256 = 63488 = 4*16*PPL/4
    int r = i - 63488;
    if (r >= 87552) return;                             // 4b * 228 border px * 96 uint4
    int b = r / 21888;
    int q = r - b*21888;
    int p = q / 96, j = q - p*96;
    int y, x;
    if (p < 58){ y=0; x=p; }
    else if (p < 116){ y=57; x=p-58; }
    else if (p < 172){ y=p-115; x=0; }
    else { y=p-171; x=57; }
    xp[(size_t)(b*PADPIX + y*PADW + x)*96 + j] = z;
  } else {
    int sb = bid - 42062;                               // [0,768)
    int c = sb % C96, s = sb / C96;
    int b = s>>1, half = s&1;
    const float4* p = (const float4*)(xin + ((size_t)(b*C96 + c))*GHW) + half*(GHW/8);
    float sum=0.f, sum2=0.f;
    for (int i=tid; i<GHW/8; i+=256){
      float4 v = p[i];
      sum  += v.x+v.y+v.z+v.w;
      sum2 += v.x*v.x+v.y*v.y+v.z*v.z+v.w*v.w;
    }
    #pragma unroll
    for (int off=32; off>0; off>>=1){ sum += __shfl_down(sum,off); sum2 += __shfl_down(sum2,off); }
    int lane=tid&63, wid=tid>>6;
    if(lane==0){ sm[wid]=sum; sm[4+wid]=sum2; }
    __syncthreads();
    if(tid==0){
      float a=sm[0]+sm[1]+sm[2]+sm[3], b2=sm[4]+sm[5]+sm[6]+sm[7];
      spart[(c*8+s)*2]   = a;
      spart[(c*8+s)*2+1] = b2;
    }
  }
}

// ---------- k_poolchan: role-split {spatial pool | channel means}, one read graph ----------
// blocks [0,416): pool (x strip = bid%13, bg = bid/13); [416,1184): chan, 4 bcg/block (1/wave).
__global__ __launch_bounds__(256) void k_poolchan(const float* __restrict__ in,
    const float* __restrict__ spart, const float* __restrict__ gamma, const float* __restrict__ beta,
    float* __restrict__ pp, float* __restrict__ sout){
  __shared__ float scs[C96], shs[C96];
  int bid = blockIdx.x, tid = threadIdx.x;
  if (bid < 416){
    if (tid < C96){
      float s=0.f, s2=0.f;
      #pragma unroll
      for (int k=0;k<8;k++){ s += spart[(tid*8+k)*2]; s2 += spart[(tid*8+k)*2+1]; }
      float mean = s*(1.f/BN_N);
      float var  = s2*(1.f/BN_N) - mean*mean;
      float sc = gamma[tid]*rsqrtf(var + 2e-5f);
      scs[tid] = sc; shs[tid] = beta[tid] - mean*sc;
    }
    __syncthreads();
    int bg = bid / 13; int b = bg>>3, g = bg&7;
    int px = (bid % 13)*256 + tid;
    if (px >= PIX) return;
    float pm0=0.f, pm1=0.f, mx0=0.f, mx1=0.f;
    for (int c = 0; c < C96; c += 2){
      size_t i0 = ((size_t)((b*C96 + c)*8 + g))*PIX + px;
      size_t i1 = i0 + (size_t)8*PIX;
      float v0 = fmaxf(fmaf(in[i0], scs[c],   shs[c]),   0.f);
      float v1 = fmaxf(fmaf(in[i1], scs[c+1], shs[c+1]), 0.f);
      pm0 += v0; mx0 = fmaxf(mx0, v0);
      pm1 += v1; mx1 = fmaxf(mx1, v1);
    }
    int y = px/HW, x = px - y*HW;
    pp[(size_t)(b*16 + g)*PPL     + (y+3)*64 + (x+3)] = pm0+pm1;
    pp[(size_t)(b*16 + 8 + g)*PPL + (y+3)*64 + (x+3)] = fmaxf(mx0,mx1);
  } else {
    int lane = tid & 63, wid = tid >> 6;
    int bcg = (bid - 416)*4 + wid;                      // [0,3072)
    int c = (bcg >> 3) % C96;
    float s=0.f, s2=0.f;
    #pragma unroll
    for (int k=0;k<8;k++){ s += spart[(c*8+k)*2]; s2 += spart[(c*8+k)*2+1]; }
    float mean = s*(1.f/BN_N);
    float var  = s2*(1.f/BN_N) - mean*mean;
    float sc = gamma[c]*rsqrtf(var + 2e-5f);
    float sh = beta[c] - mean*sc;
    const float4* p = (const float4*)(in + (size_t)bcg*PIX);
    float acc=0.f;
    for (int i=lane; i<PIX/4; i+=64){
      float4 v = p[i];
      acc += fmaxf(fmaf(v.x,sc,sh),0.f) + fmaxf(fmaf(v.y,sc,sh),0.f)
           + fmaxf(fmaf(v.z,sc,sh),0.f) + fmaxf(fmaf(v.w,sc,sh),0.f);
    }
    #pragma unroll
    for(int off=32;off>0;off>>=1) acc += __shfl_down(acc,off);
    if(lane==0) sout[bcg] = acc * (1.f/3136.f);
  }
}

// ---------- k_casp: role-split {channel attention | spatial attention conv} ----------
// blocks [0,4): ca (b=bid, 256 thr grid-stride); [4,420): sp_conv (flattened (13,32)).
__global__ __launch_bounds__(256) void k_casp(const float* __restrict__ sbuf,
    const float* __restrict__ W1, const float* __restrict__ W2,
    const float* __restrict__ pp, const float* __restrict__ Wsp,
    float* __restrict__ ach, float* __restrict__ aspt){
  __shared__ float shm[1280];        // ca: sl[768]+tl[384]; sp: wl[784]
  int bid = blockIdx.x, tid = threadIdx.x;
  if (bid < 4){
    float* sl = shm; float* tl = shm + 768;
    int b = bid;
    for (int t = tid; t < CIN; t += 256) sl[t] = sbuf[b*CIN + t];
    __syncthreads();
    int o = tid & 7;                  // invariant across t (256 % 8 == 0)
    int pg[8];
    #pragma unroll
    for (int g=0; g<8; g++) pg[g] = d_perm(o, g);
    for (int t = tid; t < NMID*8; t += 256){
      int m = t >> 3;
      float a0 = 0.f, a1 = 0.f;
      for (int c=0; c<C96; c+=2){
        #pragma unroll
        for (int g=0; g<8; g++) a0 += W1[(m*C96+c)*8+pg[g]] * sl[c*8+g];
        #pragma unroll
        for (int g=0; g<8; g++) a1 += W1[(m*C96+c+1)*8+pg[g]] * sl[(c+1)*8+g];
      }
      tl[t] = fmaxf(a0+a1, 0.f);
    }
    __syncthreads();
    for (int t = tid; t < CIN; t += 256){
      int c = t >> 3;
      float a0 = 0.f, a1 = 0.f;
      for (int m=0; m<NMID; m+=2){
        #pragma unroll
        for (int g=0; g<8; g++) a0 += W2[(c*NMID+m)*8+pg[g]] * tl[(m<<3)+g];
        #pragma unroll
        for (int g=0; g<8; g++) a1 += W2[(c*NMID+m+1)*8+pg[g]] * tl[((m+1)<<3)+g];
      }
      ach[b*CIN + t] = 1.f/(1.f+__expf(-(a0+a1)));
    }
  } else {
    float* wl = shm;
    int bid2 = bid - 4;
    int xs = bid2 % 13, bh = bid2 / 13;
    int b = bh>>3, h = bh&7;
    for(int idx=tid; idx<784; idx+=256){
      int i = idx/392; int rem = idx-i*392;
      int g = rem/49; int kk = rem-g*49;
      int dy=kk/7, dx=kk-dy*7;
      int pg = d_perm(h,g);
      int sy,sx; d_src(h,dy,dx,7,&sy,&sx);
      wl[idx] = Wsp[(i*8+pg)*49 + sy*7+sx] * (i==0 ? (1.f/96.f) : 1.f);
    }
    __syncthreads();
    int pix = xs*256 + tid;
    if(pix>=PIX) return;
    int y=pix/HW, x=pix-y*HW;
    const float* base = pp + (size_t)(b*16)*PPL + y*64 + x;
    float ac[4] = {0.f,0.f,0.f,0.f};
    #pragma unroll
    for(int ig=0; ig<16; ig++){
      const float* pb = base + (size_t)ig*PPL;
      const float* wb = wl + ig*49;
      #pragma unroll
      for(int dy=0; dy<7; dy++){
        #pragma unroll
        for(int dx=0; dx<7; dx++)
          ac[ig&3] = fmaf(pb[dy*64+dx], wb[dy*7+dx], ac[ig&3]);
      }
    }
    float acc = (ac[0]+ac[1]) + (ac[2]+ac[3]);
    aspt[((size_t)b*PIX + pix)*8 + h] = 1.f/(1.f+__expf(-acc));
  }
}

// ---------- fused bn+relu + modulate + transpose + bf16 pack ----------
__global__ __launch_bounds__(256) void k_mod_t(const float* __restrict__ in,
    const float* __restrict__ spart, const float* __restrict__ gamma, const float* __restrict__ beta,
    const float* __restrict__ ach, const float* __restrict__ aspt,
    unsigned int* __restrict__ XpU){
  __shared__ float tile[64][65];
  __shared__ float scs8[8], shs8[8];
  int b = blockIdx.z;
  int cg0 = blockIdx.y*64;
  int pix0 = blockIdx.x*64;
  int tid = threadIdx.x;
  if (tid < 8){
    int c = (cg0>>3) + tid;
    float s=0.f, s2=0.f;
    #pragma unroll
    for (int k=0;k<8;k++){ s += spart[(c*8+k)*2]; s2 += spart[(c*8+k)*2+1]; }
    float mean = s*(1.f/BN_N);
    float var  = s2*(1.f/BN_N) - mean*mean;
    float sc = gamma[c]*rsqrtf(var + 2e-5f);
    scs8[tid] = sc; shs8[tid] = beta[c] - mean*sc;
  }
  __syncthreads();
  int lane = tid & 63, w = tid >> 6;
  for (int r = w; r < 64; r += 4){
    int cg = cg0 + r;
    float a1 = ach[b*CIN + cg];
    float raw = in[(size_t)(b*CIN + cg)*PIX + pix0 + lane];
    float v = fmaxf(fmaf(raw, scs8[r>>3], shs8[r>>3]), 0.f);
    tile[r][lane] = v * a1;
  }
  __syncthreads();
  int half = lane >> 5;
  int cgA = (lane & 31)*2;
  #pragma unroll
  for (int it = 0; it < 8; it++){
    int p = it*8 + w*2 + half;
    int pix = pix0 + p;
    int y = pix/HW, x = pix - y*HW;
    float2 a2 = *(const float2*)(aspt + ((size_t)b*PIX + pix)*8 + (cgA&7));
    float vA = tile[cgA][p]   * a2.x;
    float vB = tile[cgA+1][p] * a2.y;
    unsigned int u = (unsigned int)f2bf(vA) | ((unsigned int)f2bf(vB) << 16);
    XpU[(((size_t)b*PADPIX + (y+1)*PADW + (x+1))*CIN + cg0 + cgA) >> 1] = u;
  }
}

// ---------- main conv: round-12/14 config (verified 147-149us, MfmaUtil 39%) ----------
// BM=128, K-chunk=32, 256 thr (4 waves, wave 32co x 112px). Grid 672 = 8x84 XCD-chunked.
// LDS 48KB: X dbuf 2x16KB [0,32K) + W dbuf 2x8KB [32K,48K).
// Bank swizzle g' = kg ^ ((px>>1)&3) on global SOURCE + reads (verified: conflicts=0).
// Wave w stages+reads only W rows [w*32,w*32+32) -> per-wave counted vmcnt, no W barrier.
// X[c+1] issued at kk=6; waits: kk<=5:(2), kk6,7:(6), kk8:(2); ONE barrier per chunk.
__global__ __launch_bounds__(256, 3) void k_convmf(const unsigned short* __restrict__ Xp,
    const unsigned short* __restrict__ Wt, const float* __restrict__ resid,
    float* __restrict__ out){
  __shared__ unsigned short lds[24576];   // 48KB
  char* ldsb = (char*)lds;
  int tid = threadIdx.x, lane = tid & 63, w = tid >> 6;
  int col = lane & 15, kg = lane >> 4;

  int bid = blockIdx.x;
  int wgid = (bid & 7)*84 + (bid >> 3);       // bijective XCD chunking (672 = 8*84)
  int m = wgid/112; int rem = wgid - m*112;
  int b = rem/28;  int rp = rem - b*28;
  int y0 = rp*2, co0 = m*128;

  int xgo[4], xds[4];
  #pragma unroll
  for (int t = 0; t < 4; t++){
    int slot = t*256 + tid;                   // (row, px, g)
    int row = slot >> 8;
    int px  = (slot >> 2) & 63;
    int g   = slot & 3;
    int sg  = g ^ ((px >> 1) & 3);
    xgo[t] = (b*PADPIX + (y0+row)*PADW + px)*CIN + sg*8;
    xds[t] = slot*16;                         // bytes; + xb at issue
  }
  int wgo[2], wds[2];
  #pragma unroll
  for (int j = 0; j < 2; j++){
    int r  = w*32 + j*16 + (lane>>2);
    int sg = (lane&3) ^ ((lane>>3)&3);
    wgo[j] = (co0 + r)*CIN + sg*8;
    wds[j] = 32768 + r*64 + (lane&3)*16;
  }
  int awo[2];
  #pragma unroll
  for (int mf = 0; mf < 2; mf++){
    int r = w*32 + mf*16 + col;
    awo[mf] = 32768 + r*64 + ((kg ^ ((col>>1)&3)) << 4);
  }
  int bb[3][7];
  #pragma unroll
  for (int nf=0; nf<7; nf++){
    int q2 = nf*16 + col;
    int qyl = (q2 >= 56) ? 1 : 0;
    int qx = q2 - 56*qyl;
    #pragma unroll
    for (int dx=0; dx<3; dx++){
      int px = qx + dx;
      bb[dx][nf] = qyl*4096 + px*64 + ((kg ^ ((px>>1)&3)) << 4);
    }
  }

  f32x4 acc[2][7];
  #pragma unroll
  for (int mf=0; mf<2; mf++)
    #pragma unroll
    for (int nf=0; nf<7; nf++)
      acc[mf][nf] = (f32x4){0.f,0.f,0.f,0.f};

  #pragma unroll
  for (int j = 0; j < 2; j++) gload_lds16(Wt + wgo[j], ldsb + wds[j]);
  #pragma unroll
  for (int t = 0; t < 4; t++) gload_lds16(Xp + xgo[t], ldsb + xds[t]);
  VMCNT0();
  BAR();

  int q = 0;
  for (int chunk = 0; chunk < 23; chunk++){
    const int xb = (chunk & 1) * 16384;
    #pragma unroll
    for (int kk = 0; kk < 9; kk++){
      {
        int kk2 = (kk == 8) ? 0 : kk+1;
        int c2  = (kk == 8) ? chunk+1 : chunk;
        size_t gofs = (size_t)kk2*WTK + (c2 << 5);
        int dofs = (q^1)*8192;
        gload_lds16(Wt + gofs + wgo[0], ldsb + dofs + wds[0]);
        gload_lds16(Wt + gofs + wgo[1], ldsb + dofs + wds[1]);
      }
      if (kk == 6){
        #pragma unroll
        for (int t = 0; t < 4; t++)
          gload_lds16(Xp + xgo[t] + (chunk+1)*32, ldsb + (xb^16384) + xds[t]);
      }
      if (kk == 6 || kk == 7) VMCNT6();
      else                    VMCNT2();
      const int wq = q*8192;
      bf16x8 A0 = *(const bf16x8*)(ldsb + awo[0] + wq);
      bf16x8 A1 = *(const bf16x8*)(ldsb + awo[1] + wq);
      const int dyk = kk/3, dxk = kk - dyk*3;
      const int dofs2 = xb + dyk*4096;
      __builtin_amdgcn_s_setprio(1);
      #pragma unroll
      for (int nf = 0; nf < 7; nf++){
        bf16x8 B = *(const bf16x8*)(ldsb + bb[dxk][nf] + dofs2);
        acc[0][nf] = __builtin_amdgcn_mfma_f32_16x16x32_bf16(A0, B, acc[0][nf], 0,0,0);
        acc[1][nf] = __builtin_amdgcn_mfma_f32_16x16x32_bf16(A1, B, acc[1][nf], 0,0,0);
      }
      __builtin_amdgcn_s_setprio(0);
      q ^= 1;
    }
    BAR();
  }
  {
    const int xb = 16384;
    #pragma unroll
    for (int kk = 0; kk < 9; kk++){
      if (kk < 8){
        size_t gofs = (size_t)(kk+1)*WTK + (23 << 5);
        int dofs = (q^1)*8192;
        gload_lds16(Wt + gofs + wgo[0], ldsb + dofs + wds[0]);
        gload_lds16(Wt + gofs + wgo[1], ldsb + dofs + wds[1]);
        VMCNT2();
      } else {
        VMCNT0();
      }
      const int wq = q*8192;
      bf16x8 A0 = *(const bf16x8*)(ldsb + awo[0] + wq);
      bf16x8 A1 = *(const bf16x8*)(ldsb + awo[1] + wq);
      const int dyk = kk/3, dxk = kk - dyk*3;
      const int dofs2 = xb + dyk*4096;
      __builtin_amdgcn_s_setprio(1);
      #pragma unroll
      for (int nf = 0; nf < 7; nf++){
        bf16x8 B = *(const bf16x8*)(ldsb + bb[dxk][nf] + dofs2);
        acc[0][nf] = __builtin_amdgcn_mfma_f32_16x16x32_bf16(A0, B, acc[0][nf], 0,0,0);
        acc[1][nf] = __builtin_amdgcn_mfma_f32_16x16x32_bf16(A1, B, acc[1][nf], 0,0,0);
      }
      __builtin_amdgcn_s_setprio(0);
      q ^= 1;
    }
  }

  #pragma unroll
  for (int mf = 0; mf < 2; mf++){
    int co_b = co0 + w*32 + mf*16;
    int h = co_b/C96;
    int ob = co_b - h*C96 + kg*4;
    #pragma unroll
    for (int nf = 0; nf < 7; nf++){
      int qq = nf*16 + col;
      #pragma unroll
      for (int r = 0; r < 4; r++){
        size_t oi = ((size_t)((b*C96 + ob + r)*8 + h))*PIX + y0*56 + qq;
        float v = acc[mf][nf][r];
        if (resid) v += resid[oi];
        out[oi] = v;
      }
    }
  }
}

// ---------- host side ----------
static void run_layer(const float* bn_in,
                      const float* a1W, const float* a2W, const float* spW,
                      const float* bng, const float* bnb,
                      const float* resid, float* convout,
                      float* spart, float* sbuf, float* ach, float* ppP, float* aspt,
                      unsigned short* Wt, unsigned short* Xp, hipStream_t stream)
{
  k_poolchan<<<1184,256,0,stream>>>(bn_in, spart, bng, bnb, ppP, sbuf);
  k_casp<<<420,256,0,stream>>>(sbuf, a1W, a2W, ppP, spW, ach, aspt);
  k_mod_t<<<dim3(PIX/64, CIN/64, 4),256,0,stream>>>(bn_in, spart, bng, bnb, ach, aspt, (unsigned int*)Xp);
  k_convmf<<<672,256,0,stream>>>(Xp, Wt, resid, convout);
}

extern "C" void kernel_launch(void* const* d_in, const int* in_sizes, int n_in,
                              void* d_out, int out_size, void* d_ws, size_t ws_size,
                              hipStream_t stream) {
  const float* x    = (const float*)d_in[0];
  const float* bn1g = (const float*)d_in[1];
  const float* bn1b = (const float*)d_in[2];
  const float* bn2g = (const float*)d_in[3];
  const float* bn2b = (const float*)d_in[4];
  const float* c1W  = (const float*)d_in[5];
  const float* c1a1 = (const float*)d_in[6];
  const float* c1a2 = (const float*)d_in[7];
  const float* c1sp = (const float*)d_in[8];
  const float* c2W  = (const float*)d_in[9];
  const float* c2a1 = (const float*)d_in[10];
  const float* c2a2 = (const float*)d_in[11];
  const float* c2sp = (const float*)d_in[12];
  float* out = (float*)d_out;
  float* ws  = (float*)d_ws;

  float* bufA = ws;                                          // 9,633,792 f32
  unsigned short* Wt1 = (unsigned short*)(bufA + NPIXT);     // 5,308,416 bf16
  unsigned short* Wt2 = Wt1 + 9*CIN*CIN;                     // 5,308,416 bf16
  unsigned short* Xp  = Wt2 + 9*CIN*CIN;                     // 10,334,208 bf16
  float* spart = (float*)(Xp + (size_t)4*PADPIX*CIN);        // 1536
  float* sbuf  = spart + 1536;                               // 3072
  float* ach   = sbuf + 4*C96*NG;                            // 3072
  float* ppP   = ach + 4*C96*NG;                             // 253,952 (padded pool)
  float* aspt  = ppP + 4*16*PPL;                             // 100,352
  // total ~= 83 MB

  // one launch: weight transforms + border zero + layer-1 bn stats (all independent)
  k_prep<<<42830,256,0,stream>>>(c1W, c2W, Wt1, Wt2, (uint4*)Xp, (uint4*)ppP, x, spart);

  // layer 1: bufA = conv_gg(mod(relu(bn1(x))))
  run_layer(x, c1a1, c1a2, c1sp, bn1g, bn1b, nullptr, bufA,
            spart, sbuf, ach, ppP, aspt, Wt1, Xp, stream);
  // layer 2: out = x + conv_gg(mod(relu(bn2(bufA))))
  k_bn_stats<<<dim3(C96,8),256,0,stream>>>(bufA, spart);
  run_layer(bufA, c2a1, c2a2, c2sp, bn2g, bn2b, x, out,
            spart, sbuf, ach, ppP, aspt, Wt2, Xp, stream);
}